// Round 1
// baseline (1932.688 us; speedup 1.0000x reference)
//
#include <hip/hip_runtime.h>
#include <math.h>

#define U6 6
#define BFULL 2048
#define TM 128
#define TN 128
#define TKS 16
#define LSTR 132

__device__ __forceinline__ float sigmoidf_(float x) { return 1.0f / (1.0f + expf(-x)); }

// ---------------------------------------------------------------------------
// prep: k0 = x@Wk+bk, v0 = x@Wv (no bias), q = hs@Wq_in, s0/s1 scores,
// top-4 mask, coef = mask * sigmoid(s0 - s1). 4 batches per block.
// ---------------------------------------------------------------------------
__global__ __launch_bounds__(256) void prep_kernel(
    const float* __restrict__ x, const float* __restrict__ hs,
    const float* __restrict__ Wk, const float* __restrict__ bk,
    const float* __restrict__ Wv, const float* __restrict__ bv,
    const float* __restrict__ Wq_in,
    float* __restrict__ v0, float* __restrict__ coef, float* __restrict__ maskf,
    int b0)
{
    __shared__ float xs[4][512];
    __shared__ float k0s[4][64];
    __shared__ float qs[4][384];
    __shared__ float ss[4][6], s1s[4][6];
    const int t = threadIdx.x;
    const int blb = blockIdx.x * 4;  // chunk-local batch base

    for (int j = t; j < 4 * 512; j += 256) {
        int bb = j >> 9, k = j & 511;
        xs[bb][k] = x[(size_t)(b0 + blb + bb) * 512 + k];
    }
    __syncthreads();
    {   // k0: 4*64 outputs, one per thread
        int bb = t >> 6, d = t & 63;
        float acc = 0.f;
        for (int k = 0; k < 512; ++k) acc += xs[bb][k] * Wk[k * 64 + d];
        k0s[bb][d] = acc + bk[d];
    }
    // v0: 4*400 outputs
    for (int j = t; j < 4 * 400; j += 256) {
        int bb = j / 400, v = j - bb * 400;
        float acc = 0.f;
        for (int k = 0; k < 512; ++k) acc += xs[bb][k] * Wv[k * 400 + v];
        v0[(size_t)(blb + bb) * 400 + v] = acc;
    }
    // q: 4*6*64 outputs
    for (int j = t; j < 4 * 384; j += 256) {
        int bb = j / 384, r = j - bb * 384;
        int u = r >> 6, d = r & 63;
        const float* hrow = hs + ((size_t)(b0 + blb + bb) * U6 + u) * 512;
        const float* wcol = Wq_in + ((size_t)u * 512) * 64 + d;
        float acc = 0.f;
        for (int k = 0; k < 512; ++k) acc += hrow[k] * wcol[(size_t)k * 64];
        qs[bb][r] = acc;
    }
    __syncthreads();
    if (t < 24) {
        int bb = t / 6, u = t - bb * 6;
        float a0 = 0.f, a1 = 0.f;
        for (int d = 0; d < 64; ++d) {
            float q = qs[bb][u * 64 + d];
            a0 += q * k0s[bb][d];
            a1 += q * bk[d];
        }
        ss[bb][u]  = a0 * 0.125f;   // / sqrt(64)
        s1s[bb][u] = a1 * 0.125f;
    }
    __syncthreads();
    if (t < 4) {
        int bb = t;
        bool sel[6] = {false, false, false, false, false, false};
        for (int it = 0; it < 4; ++it) {           // top-4, ties -> earliest
            int best = 0; float bm = -3.4e38f;
            for (int u = 0; u < 6; ++u)
                if (!sel[u] && ss[bb][u] > bm) { bm = ss[bb][u]; best = u; }
            sel[best] = true;
        }
        for (int u = 0; u < 6; ++u) {
            float m = sel[u] ? 1.0f : 0.0f;
            float p0 = sigmoidf_(ss[bb][u] - s1s[bb][u]);  // softmax([s0,s1])[0]
            maskf[(blb + bb) * U6 + u] = m;
            coef[(blb + bb) * U6 + u]  = m * p0;
        }
    }
}

// ---------------------------------------------------------------------------
// gates GEMM (NT): C[b,u,g] = [coef*v0 + mask*bv | hs] . [W_ih[u] | W_hh[u]]^T
// K = 400 + 512 = 912. Tile 128x128x16, 8x8 micro.
// ---------------------------------------------------------------------------
__global__ __launch_bounds__(256) void gemm_gates(
    const float* __restrict__ v0, const float* __restrict__ bv,
    const float* __restrict__ coef, const float* __restrict__ maskf,
    const float* __restrict__ hs,
    const float* __restrict__ Wih, const float* __restrict__ Whh,
    float* __restrict__ gates, int b0)
{
    __shared__ float As[TKS][LSTR];
    __shared__ float Bs[TKS][LSTR];
    const int t = threadIdx.x;
    const int tx = t & 15, ty = t >> 4;
    const int brow0 = blockIdx.x * TM;
    const int g0 = blockIdx.y * TN;
    const int u = blockIdx.z;

    const int rA0 = t >> 2, kq = t & 3;
    const float cf0 = coef[(brow0 + rA0) * U6 + u];
    const float mf0 = maskf[(brow0 + rA0) * U6 + u];
    const float cf1 = coef[(brow0 + rA0 + 64) * U6 + u];
    const float mf1 = maskf[(brow0 + rA0 + 64) * U6 + u];

    float acc[8][8];
#pragma unroll
    for (int i = 0; i < 8; ++i)
#pragma unroll
        for (int j = 0; j < 8; ++j) acc[i][j] = 0.f;

    for (int kk = 0; kk < 912; kk += TKS) {
        const int gk = kk + kq * 4;
#pragma unroll
        for (int l = 0; l < 2; ++l) {           // A tile
            int row = rA0 + l * 64;
            float4 av;
            if (gk < 400) {
                float c = l ? cf1 : cf0, m = l ? mf1 : mf0;
                const float4 vv = *(const float4*)(v0 + (size_t)(brow0 + row) * 400 + gk);
                const float4 bb = *(const float4*)(bv + gk);
                av.x = c * vv.x + m * bb.x; av.y = c * vv.y + m * bb.y;
                av.z = c * vv.z + m * bb.z; av.w = c * vv.w + m * bb.w;
            } else {
                av = *(const float4*)(hs + ((size_t)(b0 + brow0 + row) * U6 + u) * 512 + (gk - 400));
            }
            As[kq * 4 + 0][row] = av.x; As[kq * 4 + 1][row] = av.y;
            As[kq * 4 + 2][row] = av.z; As[kq * 4 + 3][row] = av.w;
        }
#pragma unroll
        for (int l = 0; l < 2; ++l) {           // B tile (weights, row-major [g,k])
            int col = rA0 + l * 64;
            float4 wv;
            if (gk < 400)
                wv = *(const float4*)(Wih + ((size_t)u * 2048 + g0 + col) * 400 + gk);
            else
                wv = *(const float4*)(Whh + ((size_t)u * 2048 + g0 + col) * 512 + (gk - 400));
            Bs[kq * 4 + 0][col] = wv.x; Bs[kq * 4 + 1][col] = wv.y;
            Bs[kq * 4 + 2][col] = wv.z; Bs[kq * 4 + 3][col] = wv.w;
        }
        __syncthreads();
#pragma unroll
        for (int k = 0; k < TKS; ++k) {
            float a[8], b[8];
            *(float4*)&a[0] = *(const float4*)&As[k][ty * 8];
            *(float4*)&a[4] = *(const float4*)&As[k][ty * 8 + 4];
            *(float4*)&b[0] = *(const float4*)&Bs[k][tx * 8];
            *(float4*)&b[4] = *(const float4*)&Bs[k][tx * 8 + 4];
#pragma unroll
            for (int i = 0; i < 8; ++i)
#pragma unroll
                for (int j = 0; j < 8; ++j) acc[i][j] += a[i] * b[j];
        }
        __syncthreads();
    }
#pragma unroll
    for (int i = 0; i < 8; ++i) {
        int rl = brow0 + ty * 8 + i;
        float* dst = gates + ((size_t)rl * U6 + u) * 2048 + g0 + tx * 8;
        *(float4*)dst       = make_float4(acc[i][0], acc[i][1], acc[i][2], acc[i][3]);
        *(float4*)(dst + 4) = make_float4(acc[i][4], acc[i][5], acc[i][6], acc[i][7]);
    }
}

// ---------------------------------------------------------------------------
// generic NN GEMM: C[row, col] = sum_k A[row,k] * B[k,col], per-u bases.
// EPI==1: Wo epilogue -> hs_out = mask ? acc + h_bg : hs (written to d_out)
// ---------------------------------------------------------------------------
template <int EPI>
__global__ __launch_bounds__(256) void gemm_nn(
    const float* __restrict__ A, int lda, int sAu,
    const float* __restrict__ Bm, int ldb, int sBu,
    float* __restrict__ C, int ldc, int sCu,
    int K,
    const float* __restrict__ maskf, const float* __restrict__ hbg,
    const float* __restrict__ hs_in, float* __restrict__ out_hs, int b0)
{
    __shared__ float As[TKS][LSTR];
    __shared__ float Bs[TKS][LSTR];
    const int t = threadIdx.x;
    const int tx = t & 15, ty = t >> 4;
    const int brow0 = blockIdx.x * TM;
    const int c0 = blockIdx.y * TN;
    const int u = blockIdx.z;
    A  += (size_t)u * sAu;
    Bm += (size_t)u * sBu;

    const int rA0 = t >> 2, kqA = t & 3;
    const int krB = t >> 5, cqB = t & 31;

    float acc[8][8];
#pragma unroll
    for (int i = 0; i < 8; ++i)
#pragma unroll
        for (int j = 0; j < 8; ++j) acc[i][j] = 0.f;

    for (int kk = 0; kk < K; kk += TKS) {
#pragma unroll
        for (int l = 0; l < 2; ++l) {           // A tile
            int row = rA0 + l * 64;
            float4 av = *(const float4*)(A + (size_t)(brow0 + row) * lda + kk + kqA * 4);
            As[kqA * 4 + 0][row] = av.x; As[kqA * 4 + 1][row] = av.y;
            As[kqA * 4 + 2][row] = av.z; As[kqA * 4 + 3][row] = av.w;
        }
#pragma unroll
        for (int l = 0; l < 2; ++l) {           // B tile ([k, col] layout)
            int kr = krB + l * 8;
            float4 wv = *(const float4*)(Bm + (size_t)(kk + kr) * ldb + c0 + cqB * 4);
            *(float4*)&Bs[kr][cqB * 4] = wv;
        }
        __syncthreads();
#pragma unroll
        for (int k = 0; k < TKS; ++k) {
            float a[8], b[8];
            *(float4*)&a[0] = *(const float4*)&As[k][ty * 8];
            *(float4*)&a[4] = *(const float4*)&As[k][ty * 8 + 4];
            *(float4*)&b[0] = *(const float4*)&Bs[k][tx * 8];
            *(float4*)&b[4] = *(const float4*)&Bs[k][tx * 8 + 4];
#pragma unroll
            for (int i = 0; i < 8; ++i)
#pragma unroll
                for (int j = 0; j < 8; ++j) acc[i][j] += a[i] * b[j];
        }
        __syncthreads();
    }

    if (EPI == 0) {
        float* Cu = C + (size_t)u * sCu;
#pragma unroll
        for (int i = 0; i < 8; ++i) {
            int rl = brow0 + ty * 8 + i;
            float* dst = Cu + (size_t)rl * ldc + c0 + tx * 8;
            *(float4*)dst       = make_float4(acc[i][0], acc[i][1], acc[i][2], acc[i][3]);
            *(float4*)(dst + 4) = make_float4(acc[i][4], acc[i][5], acc[i][6], acc[i][7]);
        }
    } else {
#pragma unroll
        for (int i = 0; i < 8; ++i) {
            int rl = brow0 + ty * 8 + i;
            float m = maskf[rl * U6 + u];
            size_t go = ((size_t)(b0 + rl) * U6 + u) * 512 + c0 + tx * 8;
            float4 o0, o1;
            if (m != 0.f) {
                const float* hb = hbg + (size_t)rl * (U6 * 512) + u * 512 + c0 + tx * 8;
                o0 = make_float4(acc[i][0] + hb[0], acc[i][1] + hb[1], acc[i][2] + hb[2], acc[i][3] + hb[3]);
                o1 = make_float4(acc[i][4] + hb[4], acc[i][5] + hb[5], acc[i][6] + hb[6], acc[i][7] + hb[7]);
            } else {
                o0 = *(const float4*)(hs_in + go);
                o1 = *(const float4*)(hs_in + go + 4);
            }
            *(float4*)(out_hs + go)     = o0;
            *(float4*)(out_hs + go + 4) = o1;
        }
    }
}

// ---------------------------------------------------------------------------
// LSTM elementwise: gates -> c_new, h_bg; writes cs_out directly to d_out
// ---------------------------------------------------------------------------
__global__ __launch_bounds__(256) void lstm_kernel(
    const float* __restrict__ gates, const float* __restrict__ b_ih,
    const float* __restrict__ b_hh, const float* __restrict__ cs,
    const float* __restrict__ maskf, float* __restrict__ h_bg,
    float* __restrict__ cs_out, int b0, int n)
{
    int idx = blockIdx.x * 256 + threadIdx.x;
    if (idx >= n) return;
    int bl = idx / 3072;
    int r = idx - bl * 3072;
    int u = r >> 9, h = r & 511;
    const float* g = gates + (size_t)bl * 12288 + u * 2048;
    int gb = u * 2048;
    float i_ = g[h]        + b_ih[gb + h]        + b_hh[gb + h];
    float f_ = g[512 + h]  + b_ih[gb + 512 + h]  + b_hh[gb + 512 + h];
    float g_ = g[1024 + h] + b_ih[gb + 1024 + h] + b_hh[gb + 1024 + h];
    float o_ = g[1536 + h] + b_ih[gb + 1536 + h] + b_hh[gb + 1536 + h];
    float c = cs[((size_t)(b0 + bl) * U6 + u) * 512 + h];
    float cn = sigmoidf_(f_) * c + sigmoidf_(i_) * tanhf(g_);
    h_bg[idx] = sigmoidf_(o_) * tanhf(cn);
    float m = maskf[bl * U6 + u];
    cs_out[((size_t)(b0 + bl) * U6 + u) * 512 + h] = (m != 0.f) ? cn : c;
}

// ---------------------------------------------------------------------------
// tiny attention: per (batch, head): att = softmax(q k^T / sqrt(32)) * mask,
// ctx = att @ v
// ---------------------------------------------------------------------------
__global__ __launch_bounds__(256) void attn_kernel(
    const float* __restrict__ qk, const float* __restrict__ vbuf,
    const float* __restrict__ maskf, float* __restrict__ ctx)
{
    const int bl = blockIdx.x, hh = blockIdx.y, t = threadIdx.x;
    __shared__ float qs[6][32], ks[6][32], att[6][8];
    if (t < 192) {
        int u = t >> 5, d = t & 31;
        qs[u][d] = qk[(size_t)(bl * U6 + u) * 256 + hh * 32 + d];
        ks[u][d] = qk[(size_t)(bl * U6 + u) * 256 + 128 + hh * 32 + d];
    }
    __syncthreads();
    if (t < 36) {
        int u = t / 6, n = t - (t / 6) * 6;
        float a = 0.f;
        for (int d = 0; d < 32; ++d) a += qs[u][d] * ks[n][d];
        att[u][n] = a / sqrtf(32.0f);
    }
    __syncthreads();
    if (t < 6) {
        float mx = att[t][0];
        for (int n = 1; n < 6; ++n) mx = fmaxf(mx, att[t][n]);
        float e[6], s = 0.f;
        for (int n = 0; n < 6; ++n) { e[n] = expf(att[t][n] - mx); s += e[n]; }
        float mk = maskf[bl * U6 + t];
        for (int n = 0; n < 6; ++n) att[t][n] = e[n] / s * mk;
    }
    __syncthreads();
    for (int e0 = t; e0 < 512; e0 += 256) {
        float vv[6];
#pragma unroll
        for (int n = 0; n < 6; ++n) vv[n] = vbuf[(size_t)(bl * U6 + n) * 2048 + hh * 512 + e0];
#pragma unroll
        for (int u = 0; u < 6; ++u) {
            float a = 0.f;
#pragma unroll
            for (int n = 0; n < 6; ++n) a += att[u][n] * vv[n];
            ctx[(size_t)(bl * U6 + u) * 2048 + hh * 512 + e0] = a;
        }
    }
}

// ---------------------------------------------------------------------------
extern "C" void kernel_launch(void* const* d_in, const int* in_sizes, int n_in,
                              void* d_out, int out_size, void* d_ws, size_t ws_size,
                              hipStream_t stream)
{
    const float* x     = (const float*)d_in[0];
    const float* hs    = (const float*)d_in[1];
    const float* cs    = (const float*)d_in[2];
    const float* Wk    = (const float*)d_in[3];
    const float* bk    = (const float*)d_in[4];
    const float* Wv    = (const float*)d_in[5];
    const float* bv    = (const float*)d_in[6];
    const float* Wq_in = (const float*)d_in[7];
    const float* Wq_c  = (const float*)d_in[8];
    const float* Wk_c  = (const float*)d_in[9];
    const float* Wv_c  = (const float*)d_in[10];
    const float* Wo_c  = (const float*)d_in[11];
    const float* W_ih  = (const float*)d_in[12];
    const float* W_hh  = (const float*)d_in[13];
    const float* b_ih  = (const float*)d_in[14];
    const float* b_hh  = (const float*)d_in[15];

    float* out_hs = (float*)d_out;
    float* out_cs = out_hs + (size_t)BFULL * U6 * 512;

    // adaptive batch chunking so scratch fits ws_size
    // per-chunk floats: 400 + 6 + 6 + 3072 + 12288 + 12288 + 1536 = 29596 per batch row
    int NC = 1;
    while (NC < 16) {
        size_t Bc = BFULL / NC;
        if (Bc * 29596ull * 4ull <= ws_size) break;
        NC *= 2;
    }
    const int Bc = BFULL / NC;

    float* w     = (float*)d_ws;
    float* v0    = w;
    float* coef  = v0 + (size_t)Bc * 400;
    float* maskf = coef + (size_t)Bc * U6;
    float* hbg   = maskf + (size_t)Bc * U6;
    float* regA  = hbg + (size_t)Bc * 3072;          // gates, then v
    float* regB  = regA + (size_t)Bc * 12288;        // ctx
    float* qkbuf = regB + (size_t)Bc * 12288;        // (Bc, U, 256): q | k

    for (int c = 0; c < NC; ++c) {
        const int b0 = c * Bc;
        prep_kernel<<<Bc / 4, 256, 0, stream>>>(x, hs, Wk, bk, Wv, bv, Wq_in,
                                                v0, coef, maskf, b0);
        gemm_gates<<<dim3(Bc / 128, 16, U6), 256, 0, stream>>>(
            v0, bv, coef, maskf, hs, W_ih, W_hh, regA, b0);
        {
            int n = Bc * 3072;
            lstm_kernel<<<(n + 255) / 256, 256, 0, stream>>>(
                regA, b_ih, b_hh, cs, maskf, hbg, out_cs, b0, n);
        }
        // q and k projections (N = 128 each)
        gemm_nn<0><<<dim3(Bc / 128, 1, U6), 256, 0, stream>>>(
            hbg, 3072, 512, Wq_c, 128, 512 * 128, qkbuf, 1536, 256, 512,
            nullptr, nullptr, nullptr, nullptr, 0);
        gemm_nn<0><<<dim3(Bc / 128, 1, U6), 256, 0, stream>>>(
            hbg, 3072, 512, Wk_c, 128, 512 * 128, qkbuf + 128, 1536, 256, 512,
            nullptr, nullptr, nullptr, nullptr, 0);
        // v projection (N = 2048) into regA (gates no longer needed)
        gemm_nn<0><<<dim3(Bc / 128, 16, U6), 256, 0, stream>>>(
            hbg, 3072, 512, Wv_c, 2048, 512 * 2048, regA, 12288, 2048, 512,
            nullptr, nullptr, nullptr, nullptr, 0);
        attn_kernel<<<dim3(Bc, 4), 256, 0, stream>>>(qkbuf, regA, maskf, regB);
        // output projection + residual + mask-select, straight to d_out
        gemm_nn<1><<<dim3(Bc / 128, 4, U6), 256, 0, stream>>>(
            regB, 12288, 2048, Wo_c, 512, 2048 * 512, nullptr, 0, 0, 2048,
            maskf, hbg, hs, out_hs, b0);
    }
}

// Round 3
// 805.834 us; speedup vs baseline: 2.3984x; 2.3984x over previous
//
#include <hip/hip_runtime.h>
#include <math.h>

#define U6 6
#define BFULL 2048

typedef __bf16 bf16;
typedef __bf16 bf16x8 __attribute__((ext_vector_type(8)));
typedef float f32x4 __attribute__((ext_vector_type(4)));

__device__ __forceinline__ float sigmoidf_(float x) { return 1.0f / (1.0f + expf(-x)); }

// ---------------------------------------------------------------------------
// prep: k0 = x@Wk+bk, v0 = x@Wv (LDS only), q = hs@Wq_in, s0/s1 scores,
// top-4 mask, coef = mask * sigmoid(s0 - s1). Builds bf16 gates-A matrix
// A_g[b][u][928] = [coef*v0 + mask*bv | hs | 0-pad]. 4 batches per block.
// ---------------------------------------------------------------------------
__global__ __launch_bounds__(256) void prep_kernel(
    const float* __restrict__ x, const float* __restrict__ hs,
    const float* __restrict__ Wk, const float* __restrict__ bk,
    const float* __restrict__ Wv, const float* __restrict__ bv,
    const float* __restrict__ Wq_in,
    bf16* __restrict__ A_g, float* __restrict__ coef, float* __restrict__ maskf,
    int b0)
{
    __shared__ float xs[4][512];
    __shared__ float v0s[4][400];
    __shared__ float k0s[4][64];
    __shared__ float qs[4][384];
    __shared__ float ss[4][6], s1s[4][6], cls[4][6], mls[4][6];
    const int t = threadIdx.x;
    const int blb = blockIdx.x * 4;  // chunk-local batch base

    for (int j = t; j < 4 * 512; j += 256) {
        int bb = j >> 9, k = j & 511;
        xs[bb][k] = x[(size_t)(b0 + blb + bb) * 512 + k];
    }
    __syncthreads();
    {   // k0: 4*64 outputs, one per thread
        int bb = t >> 6, d = t & 63;
        float acc = 0.f;
        for (int k = 0; k < 512; ++k) acc += xs[bb][k] * Wk[k * 64 + d];
        k0s[bb][d] = acc + bk[d];
    }
    // v0: 4*400 outputs -> LDS
    for (int j = t; j < 4 * 400; j += 256) {
        int bb = j / 400, v = j - bb * 400;
        float acc = 0.f;
        for (int k = 0; k < 512; ++k) acc += xs[bb][k] * Wv[k * 400 + v];
        v0s[bb][v] = acc;
    }
    // q: 4*6*64 outputs
    for (int j = t; j < 4 * 384; j += 256) {
        int bb = j / 384, r = j - bb * 384;
        int u = r >> 6, d = r & 63;
        const float* hrow = hs + ((size_t)(b0 + blb + bb) * U6 + u) * 512;
        const float* wcol = Wq_in + ((size_t)u * 512) * 64 + d;
        float acc = 0.f;
        for (int k = 0; k < 512; ++k) acc += hrow[k] * wcol[(size_t)k * 64];
        qs[bb][r] = acc;
    }
    __syncthreads();
    if (t < 24) {
        int bb = t / 6, u = t - bb * 6;
        float a0 = 0.f, a1 = 0.f;
        for (int d = 0; d < 64; ++d) {
            float q = qs[bb][u * 64 + d];
            a0 += q * k0s[bb][d];
            a1 += q * bk[d];
        }
        ss[bb][u]  = a0 * 0.125f;   // / sqrt(64)
        s1s[bb][u] = a1 * 0.125f;
    }
    __syncthreads();
    if (t < 4) {
        int bb = t;
        bool sel[6] = {false, false, false, false, false, false};
        for (int it = 0; it < 4; ++it) {           // top-4, ties -> earliest
            int best = 0; float bm = -3.4e38f;
            for (int u = 0; u < 6; ++u)
                if (!sel[u] && ss[bb][u] > bm) { bm = ss[bb][u]; best = u; }
            sel[best] = true;
        }
        for (int u = 0; u < 6; ++u) {
            float m = sel[u] ? 1.0f : 0.0f;
            float p0 = sigmoidf_(ss[bb][u] - s1s[bb][u]);  // softmax([s0,s1])[0]
            maskf[(blb + bb) * U6 + u] = m;
            coef[(blb + bb) * U6 + u]  = m * p0;
            mls[bb][u] = m;
            cls[bb][u] = m * p0;
        }
    }
    __syncthreads();
    // build bf16 A_g: [coef*v0 + mask*bv | hs | 0]
    for (int j = t; j < 4 * 6 * 928; j += 256) {
        int bb = j / 5568, r = j - bb * 5568;
        int u = r / 928, k = r - u * 928;
        float val;
        if (k < 400)       val = cls[bb][u] * v0s[bb][k] + mls[bb][u] * bv[k];
        else if (k < 912)  val = hs[((size_t)(b0 + blb + bb) * U6 + u) * 512 + (k - 400)];
        else               val = 0.f;
        A_g[((size_t)(blb + bb) * U6 + u) * 928 + k] = (bf16)val;
    }
}

// ---------------------------------------------------------------------------
// weight prep: Wg[u][g][928] = bf16 concat(W_ih[u][g][0:400], W_hh[u][g][0:512], 0)
// ---------------------------------------------------------------------------
__global__ __launch_bounds__(256) void build_wg(
    const float* __restrict__ Wih, const float* __restrict__ Whh,
    bf16* __restrict__ Wg)
{
    size_t idx = (size_t)blockIdx.x * 256 + threadIdx.x;
    if (idx >= 6UL * 2048 * 928) return;
    int u = (int)(idx / (2048 * 928));
    int r = (int)(idx % (2048 * 928));
    int g = r / 928, k = r - g * 928;
    float v = 0.f;
    if (k < 400)      v = Wih[((size_t)u * 2048 + g) * 400 + k];
    else if (k < 912) v = Whh[((size_t)u * 2048 + g) * 512 + (k - 400)];
    Wg[idx] = (bf16)v;
}

// ---------------------------------------------------------------------------
// transpose+convert: in[u][K][N] f32 (n contiguous) -> out[u][n0base+n][K] bf16
// ---------------------------------------------------------------------------
__global__ __launch_bounds__(256) void transpose_cvt(
    const float* __restrict__ in, bf16* __restrict__ out,
    int Kdim, int Ndim, int n0base, long sInU, long sOutU)
{
    __shared__ float tile[32][33];
    const int t = threadIdx.x;
    const int c = t & 31, r8 = t >> 5;
    const int n0 = blockIdx.x * 32, k0 = blockIdx.y * 32, u = blockIdx.z;
    in  += (size_t)u * sInU;
    out += (size_t)u * sOutU;
    for (int rr = r8; rr < 32; rr += 8)
        tile[rr][c] = in[(size_t)(k0 + rr) * Ndim + n0 + c];
    __syncthreads();
    for (int rr = r8; rr < 32; rr += 8)
        out[(size_t)(n0base + n0 + rr) * Kdim + k0 + c] = (bf16)tile[c][rr];
}

// ---------------------------------------------------------------------------
// bf16 MFMA GEMM: C[row][n] = sum_k A[row][k] * B[n][k]
// 128x128 tile, BK=32, 4 waves (2x2), each wave 64x64 = 4x4 16x16 frags.
// LDS slot-swizzled (slot ^= (row>>1)&3) -> conflict-free b128 read+write.
// EPI==1: Wo epilogue -> out_hs = mask ? acc + hbg : hs_in
// ---------------------------------------------------------------------------
template <int EPI>
__global__ __launch_bounds__(256) void gemm_mfma(
    const bf16* __restrict__ A, int lda, long sAu,
    const bf16* __restrict__ B, long sBu,
    float* __restrict__ C, int ldc, long sCu,
    int K,
    const float* __restrict__ maskf, const float* __restrict__ hbg,
    const float* __restrict__ hs_in, float* __restrict__ out_hs, int b0)
{
    __shared__ bf16 Abuf[128 * 32];
    __shared__ bf16 Bbuf[128 * 32];
    const int t = threadIdx.x;
    const int wid = t >> 6, lane = t & 63;
    const int wr = wid >> 1, wc = wid & 1;
    const int brow0 = blockIdx.x * 128;
    const int c0 = blockIdx.y * 128;
    const int u = blockIdx.z;
    A += (size_t)u * sAu;
    B += (size_t)u * sBu;

    // staging: 512 chunks of 16B (128 rows x 4 slots); thread t -> chunks t, t+256
    const int r0 = t >> 2, s0 = t & 3;
    const int r1 = r0 + 64;
    const int lo0 = r0 * 32 + ((s0 ^ ((r0 >> 1) & 3)) << 3);
    const int lo1 = r1 * 32 + ((s0 ^ ((r1 >> 1) & 3)) << 3);

    const bf16* Ap0 = A + (size_t)(brow0 + r0) * lda + s0 * 8;
    const bf16* Ap1 = A + (size_t)(brow0 + r1) * lda + s0 * 8;
    const bf16* Bp0 = B + (size_t)(c0 + r0) * K + s0 * 8;
    const bf16* Bp1 = B + (size_t)(c0 + r1) * K + s0 * 8;

    f32x4 acc[4][4];
#pragma unroll
    for (int m = 0; m < 4; ++m)
#pragma unroll
        for (int n = 0; n < 4; ++n) {
            f32x4 z = {0.f, 0.f, 0.f, 0.f};
            acc[m][n] = z;
        }

    const int nk = K >> 5;
    uint4 pa0 = *(const uint4*)(Ap0);
    uint4 pa1 = *(const uint4*)(Ap1);
    uint4 pb0 = *(const uint4*)(Bp0);
    uint4 pb1 = *(const uint4*)(Bp1);

    const int kg = lane >> 4;      // k-group 0..3
    const int lr = lane & 15;

    for (int ks = 0; ks < nk; ++ks) {
        uint4 ca0 = pa0, ca1 = pa1, cb0 = pb0, cb1 = pb1;
        if (ks + 1 < nk) {
            const int kk = (ks + 1) << 5;
            pa0 = *(const uint4*)(Ap0 + kk);
            pa1 = *(const uint4*)(Ap1 + kk);
            pb0 = *(const uint4*)(Bp0 + kk);
            pb1 = *(const uint4*)(Bp1 + kk);
        }
        __syncthreads();
        *(uint4*)&Abuf[lo0] = ca0;
        *(uint4*)&Abuf[lo1] = ca1;
        *(uint4*)&Bbuf[lo0] = cb0;
        *(uint4*)&Bbuf[lo1] = cb1;
        __syncthreads();

        bf16x8 af[4], bfr[4];
#pragma unroll
        for (int m = 0; m < 4; ++m) {
            const int row = wr * 64 + m * 16 + lr;
            af[m] = *(bf16x8*)&Abuf[row * 32 + ((kg ^ ((row >> 1) & 3)) << 3)];
            const int col = wc * 64 + m * 16 + lr;
            bfr[m] = *(bf16x8*)&Bbuf[col * 32 + ((kg ^ ((col >> 1) & 3)) << 3)];
        }
#pragma unroll
        for (int m = 0; m < 4; ++m)
#pragma unroll
            for (int n = 0; n < 4; ++n)
                acc[m][n] = __builtin_amdgcn_mfma_f32_16x16x32_bf16(af[m], bfr[n], acc[m][n], 0, 0, 0);
    }

    // epilogue: C/D layout col = lane&15, row = (lane>>4)*4 + r
#pragma unroll
    for (int m = 0; m < 4; ++m) {
#pragma unroll
        for (int n = 0; n < 4; ++n) {
#pragma unroll
            for (int r = 0; r < 4; ++r) {
                const int row = brow0 + wr * 64 + m * 16 + kg * 4 + r;
                const int col = c0 + wc * 64 + n * 16 + lr;
                const float v = acc[m][n][r];
                if (EPI == 0) {
                    C[(size_t)u * sCu + (size_t)row * ldc + col] = v;
                } else {
                    const float mv = maskf[row * U6 + u];
                    const size_t go = ((size_t)(b0 + row) * U6 + u) * 512 + col;
                    out_hs[go] = (mv != 0.f)
                        ? v + hbg[(size_t)row * 3072 + u * 512 + col]
                        : hs_in[go];
                }
            }
        }
    }
}

// ---------------------------------------------------------------------------
// LSTM elementwise: gates -> c_new, h_bg (f32 + bf16); cs_out direct to d_out
// ---------------------------------------------------------------------------
__global__ __launch_bounds__(256) void lstm_kernel(
    const float* __restrict__ gates, const float* __restrict__ b_ih,
    const float* __restrict__ b_hh, const float* __restrict__ cs,
    const float* __restrict__ maskf, float* __restrict__ h_bg,
    bf16* __restrict__ h16, float* __restrict__ cs_out, int b0, int n)
{
    int idx = blockIdx.x * 256 + threadIdx.x;
    if (idx >= n) return;
    int bl = idx / 3072;
    int r = idx - bl * 3072;
    int u = r >> 9, h = r & 511;
    const float* g = gates + (size_t)bl * 12288 + u * 2048;
    int gb = u * 2048;
    float i_ = g[h]        + b_ih[gb + h]        + b_hh[gb + h];
    float f_ = g[512 + h]  + b_ih[gb + 512 + h]  + b_hh[gb + 512 + h];
    float g_ = g[1024 + h] + b_ih[gb + 1024 + h] + b_hh[gb + 1024 + h];
    float o_ = g[1536 + h] + b_ih[gb + 1536 + h] + b_hh[gb + 1536 + h];
    float c = cs[((size_t)(b0 + bl) * U6 + u) * 512 + h];
    float cn = sigmoidf_(f_) * c + sigmoidf_(i_) * tanhf(g_);
    float hv = sigmoidf_(o_) * tanhf(cn);
    h_bg[idx] = hv;
    h16[idx] = (bf16)hv;
    float m = maskf[bl * U6 + u];
    cs_out[((size_t)(b0 + bl) * U6 + u) * 512 + h] = (m != 0.f) ? cn : c;
}

// ---------------------------------------------------------------------------
// tiny attention over qkv fused layout: qkv[bl][u*2304 + (q:128|k:128|v:2048)]
// with per-batch row stride 13824 floats. ctx written in bf16.
// ---------------------------------------------------------------------------
__global__ __launch_bounds__(256) void attn_kernel(
    const float* __restrict__ qkv, bf16* __restrict__ ctx)
{
    const int bl = blockIdx.x, hh = blockIdx.y, t = threadIdx.x;
    __shared__ float qs[6][32], ks[6][32], att[6][8];
    if (t < 192) {
        int u = t >> 5, d = t & 31;
        const size_t rowb = (size_t)bl * 13824 + (size_t)u * 2304;  // FIXED stride
        qs[u][d] = qkv[rowb + hh * 32 + d];
        ks[u][d] = qkv[rowb + 128 + hh * 32 + d];
    }
    __syncthreads();
    if (t < 36) {
        int u = t / 6, n = t - (t / 6) * 6;
        float a = 0.f;
        for (int d = 0; d < 32; ++d) a += qs[u][d] * ks[n][d];
        att[u][n] = a * 0.17677669529663687f;  // 1/sqrt(32)
    }
    __syncthreads();
    if (t < 6) {
        float mx = att[t][0];
        for (int n = 1; n < 6; ++n) mx = fmaxf(mx, att[t][n]);
        float e[6], s = 0.f;
        for (int n = 0; n < 6; ++n) { e[n] = expf(att[t][n] - mx); s += e[n]; }
        for (int n = 0; n < 6; ++n) att[t][n] = e[n] / s;
    }
    __syncthreads();
    for (int e0 = t; e0 < 512; e0 += 256) {
        float vv[6];
#pragma unroll
        for (int n = 0; n < 6; ++n)
            vv[n] = qkv[(size_t)bl * 13824 + (size_t)n * 2304 + 256 + hh * 512 + e0];
#pragma unroll
        for (int u = 0; u < 6; ++u) {
            float a = 0.f;
#pragma unroll
            for (int n = 0; n < 6; ++n) a += att[u][n] * vv[n];
            ctx[((size_t)bl * U6 + u) * 2048 + hh * 512 + e0] = (bf16)a;
        }
    }
}

// ---------------------------------------------------------------------------
extern "C" void kernel_launch(void* const* d_in, const int* in_sizes, int n_in,
                              void* d_out, int out_size, void* d_ws, size_t ws_size,
                              hipStream_t stream)
{
    const float* x     = (const float*)d_in[0];
    const float* hs    = (const float*)d_in[1];
    const float* cs    = (const float*)d_in[2];
    const float* Wk    = (const float*)d_in[3];
    const float* bk    = (const float*)d_in[4];
    const float* Wv    = (const float*)d_in[5];
    const float* bv    = (const float*)d_in[6];
    const float* Wq_in = (const float*)d_in[7];
    const float* Wq_c  = (const float*)d_in[8];
    const float* Wk_c  = (const float*)d_in[9];
    const float* Wv_c  = (const float*)d_in[10];
    const float* Wo_c  = (const float*)d_in[11];
    const float* W_ih  = (const float*)d_in[12];
    const float* W_hh  = (const float*)d_in[13];
    const float* b_ih  = (const float*)d_in[14];
    const float* b_hh  = (const float*)d_in[15];

    float* out_hs = (float*)d_out;
    float* out_cs = out_hs + (size_t)BFULL * U6 * 512;

    // ---- workspace layout ----
    const size_t wgB   = 6UL * 2048 * 928 * 2;   // Wg bf16
    const size_t wqkvB = 6UL * 2304 * 512 * 2;   // Wqkv bf16 (q|k|v rows, [n][k])
    const size_t woB   = 6UL * 512 * 2048 * 2;   // WoT bf16
    const size_t weightsB = ((wgB + 255) & ~255UL) + ((wqkvB + 255) & ~255UL)
                          + ((woB + 255) & ~255UL);
    const size_t perRow = 55296 + 24576 + 12288 + 6144 + 24 + 24 + 64; // R1+R2+hbg+h16+coef+mask
    int NC = 1;
    while (NC < 16 && weightsB + (size_t)(BFULL / NC) * perRow + 8192 > ws_size) NC *= 2;
    const int Bc = BFULL / NC;

    size_t off = 0;
    auto alloc = [&](size_t bytes) {
        void* p = (char*)d_ws + off;
        off = (off + bytes + 255) & ~255UL;
        return p;
    };
    bf16*  Wg    = (bf16*)alloc(wgB);
    bf16*  Wqkv  = (bf16*)alloc(wqkvB);
    bf16*  WoT   = (bf16*)alloc(woB);
    float* R1    = (float*)alloc((size_t)Bc * 55296);  // gates f32, then qkv f32
    bf16*  R2    = (bf16*)alloc((size_t)Bc * 24576);   // A_g bf16, then ctx bf16
    float* hbg   = (float*)alloc((size_t)Bc * 12288);
    bf16*  h16   = (bf16*)alloc((size_t)Bc * 6144);
    float* coef  = (float*)alloc((size_t)Bc * 24);
    float* maskf = (float*)alloc((size_t)Bc * 24);

    float* gates = R1;
    float* qkv   = R1;
    bf16*  A_g   = R2;
    bf16*  ctx16 = R2;

    // ---- once per call: bf16 weight builds ----
    {
        size_t n = 6UL * 2048 * 928;
        build_wg<<<(int)((n + 255) / 256), 256, 0, stream>>>(W_ih, W_hh, Wg);
    }
    transpose_cvt<<<dim3(4, 16, U6), 256, 0, stream>>>(Wq_c, Wqkv, 512, 128, 0,
                                                       512L * 128, 2304L * 512);
    transpose_cvt<<<dim3(4, 16, U6), 256, 0, stream>>>(Wk_c, Wqkv, 512, 128, 128,
                                                       512L * 128, 2304L * 512);
    transpose_cvt<<<dim3(64, 16, U6), 256, 0, stream>>>(Wv_c, Wqkv, 512, 2048, 256,
                                                        512L * 2048, 2304L * 512);
    transpose_cvt<<<dim3(16, 64, U6), 256, 0, stream>>>(Wo_c, WoT, 2048, 512, 0,
                                                        2048L * 512, 512L * 2048);

    for (int c = 0; c < NC; ++c) {
        const int b0 = c * Bc;
        prep_kernel<<<Bc / 4, 256, 0, stream>>>(x, hs, Wk, bk, Wv, bv, Wq_in,
                                                A_g, coef, maskf, b0);
        // gates = A_g @ Wg^T   (M=Bc, N=2048, K=928)
        gemm_mfma<0><<<dim3(Bc / 128, 16, U6), 256, 0, stream>>>(
            A_g, 5568, 928L, Wg, 2048L * 928, gates, 12288, 2048L, 928,
            nullptr, nullptr, nullptr, nullptr, 0);
        {
            int n = Bc * 3072;
            lstm_kernel<<<(n + 255) / 256, 256, 0, stream>>>(
                gates, b_ih, b_hh, cs, maskf, hbg, h16, out_cs, b0, n);
        }
        // qkv = h16 @ Wqkv^T   (M=Bc, N=2304, K=512) -> overwrites gates region
        gemm_mfma<0><<<dim3(Bc / 128, 18, U6), 256, 0, stream>>>(
            h16, 3072, 512L, Wqkv, 2304L * 512, qkv, 13824, 2304L, 512,
            nullptr, nullptr, nullptr, nullptr, 0);
        attn_kernel<<<dim3(Bc, 4), 256, 0, stream>>>(qkv, ctx16);
        // hs_out = mask ? ctx @ WoT^T + hbg : hs   (M=Bc, N=512, K=2048)
        gemm_mfma<1><<<dim3(Bc / 128, 4, U6), 256, 0, stream>>>(
            ctx16, 12288, 2048L, WoT, 512L * 2048, nullptr, 0, 0L, 2048,
            maskf, hbg, hs, out_hs, b0);
    }
}

// Round 4
// 628.153 us; speedup vs baseline: 3.0768x; 1.2829x over previous
//
#include <hip/hip_runtime.h>
#include <math.h>

#define U6 6
#define BFULL 2048

typedef __bf16 bf16;
typedef __bf16 bf16x8 __attribute__((ext_vector_type(8)));
typedef float f32x4 __attribute__((ext_vector_type(4)));

__device__ __forceinline__ float sigmoidf_(float x) { return 1.0f / (1.0f + expf(-x)); }

// ---------------------------------------------------------------------------
// score kernel (fp32, full batch): k0 = x@Wk+bk, q = hs@Wq_in, s0 = q.k0/8,
// s1 = q.bk/8, top-4 mask, coef = mask*sigmoid(s0-s1).
// 8 batches per block, 384 threads = 6 waves; wave u, lane d.
// ---------------------------------------------------------------------------
__global__ __launch_bounds__(384) void score_kernel(
    const float* __restrict__ x, const float* __restrict__ hs,
    const float* __restrict__ Wk, const float* __restrict__ bk,
    const float* __restrict__ Wq_in,
    float* __restrict__ coef, float* __restrict__ maskf)
{
    __shared__ float xt[8][128];
    __shared__ float hst[8][6][128];
    __shared__ float ss[8][6], s1s[8][6];
    const int t = threadIdx.x;
    const int u = t >> 6, d = t & 63;   // wave u, lane d
    const int b8 = blockIdx.x * 8;

    float k0a[8] = {0,0,0,0,0,0,0,0};
    float qa[8]  = {0,0,0,0,0,0,0,0};

    for (int kt = 0; kt < 4; ++kt) {
        __syncthreads();
        for (int j = t; j < 1024; j += 384) {           // stage x k-tile
            int bb = j >> 7, kk = j & 127;
            xt[bb][kk] = x[(size_t)(b8 + bb) * 512 + kt * 128 + kk];
        }
        for (int j = t; j < 6144; j += 384) {           // stage hs k-tile
            int bb = j / 768, r = j - bb * 768;
            int uu = r >> 7, kk = r & 127;
            hst[bb][uu][kk] = hs[((size_t)(b8 + bb) * U6 + uu) * 512 + kt * 128 + kk];
        }
        __syncthreads();
        for (int kk = 0; kk < 128; ++kk) {
            int k = kt * 128 + kk;
            float wk = Wk[k * 64 + d];
            float wq = Wq_in[((size_t)u * 512 + k) * 64 + d];
#pragma unroll
            for (int b = 0; b < 8; ++b) {
                k0a[b] += xt[b][kk] * wk;
                qa[b]  += hst[b][u][kk] * wq;
            }
        }
    }
    float bkd = bk[d];
    float s0[8], s1[8];
#pragma unroll
    for (int b = 0; b < 8; ++b) {
        float k0f = k0a[b] + bkd;
        s0[b] = qa[b] * k0f;
        s1[b] = qa[b] * bkd;
    }
#pragma unroll
    for (int off = 32; off > 0; off >>= 1) {
#pragma unroll
        for (int b = 0; b < 8; ++b) {
            s0[b] += __shfl_xor(s0[b], off, 64);
            s1[b] += __shfl_xor(s1[b], off, 64);
        }
    }
    if (d == 0) {
#pragma unroll
        for (int b = 0; b < 8; ++b) { ss[b][u] = s0[b] * 0.125f; s1s[b][u] = s1[b] * 0.125f; }
    }
    __syncthreads();
    if (t < 8) {
        int bb = t;
        bool sel[6] = {false,false,false,false,false,false};
        for (int it = 0; it < 4; ++it) {                // top-4, ties -> earliest
            int best = 0; float bm = -3.4e38f;
            for (int uu = 0; uu < 6; ++uu)
                if (!sel[uu] && ss[bb][uu] > bm) { bm = ss[bb][uu]; best = uu; }
            sel[best] = true;
        }
        for (int uu = 0; uu < 6; ++uu) {
            float m = sel[uu] ? 1.f : 0.f;
            float p0 = sigmoidf_(ss[bb][uu] - s1s[bb][uu]);
            maskf[(b8 + bb) * U6 + uu] = m;
            coef[(b8 + bb) * U6 + uu]  = m * p0;
        }
    }
}

// ---------------------------------------------------------------------------
// weight prep: Wg[u][g][928] = bf16 concat(W_ih[u][g][0:400], W_hh[u][g][0:512], 0)
// ---------------------------------------------------------------------------
__global__ __launch_bounds__(256) void build_wg(
    const float* __restrict__ Wih, const float* __restrict__ Whh,
    bf16* __restrict__ Wg)
{
    size_t idx = (size_t)blockIdx.x * 256 + threadIdx.x;
    if (idx >= 6UL * 2048 * 928) return;
    int u = (int)(idx / (2048 * 928));
    int r = (int)(idx % (2048 * 928));
    int g = r / 928, k = r - g * 928;
    float v = 0.f;
    if (k < 400)      v = Wih[((size_t)u * 2048 + g) * 400 + k];
    else if (k < 912) v = Whh[((size_t)u * 2048 + g) * 512 + (k - 400)];
    Wg[idx] = (bf16)v;
}

// ---------------------------------------------------------------------------
// transpose+convert: in[u][K][Nvalid] f32 -> out[u][n0base+n][K] bf16
// rows n >= Nvalid are zero-filled (N padding).
// ---------------------------------------------------------------------------
__global__ __launch_bounds__(256) void transpose_cvt(
    const float* __restrict__ in, bf16* __restrict__ out,
    int Kdim, int Ndim, int Nvalid, int n0base, long sInU, long sOutU)
{
    __shared__ float tile[32][33];
    const int t = threadIdx.x;
    const int c = t & 31, r8 = t >> 5;
    const int n0 = blockIdx.x * 32, k0 = blockIdx.y * 32, u = blockIdx.z;
    in  += (size_t)u * sInU;
    out += (size_t)u * sOutU;
    for (int rr = r8; rr < 32; rr += 8)
        tile[rr][c] = (n0 + c < Nvalid) ? in[(size_t)(k0 + rr) * Ndim + n0 + c] : 0.f;
    __syncthreads();
    for (int rr = r8; rr < 32; rr += 8)
        out[(size_t)(n0base + n0 + rr) * Kdim + k0 + c] = (bf16)tile[c][rr];
}

// ---------------------------------------------------------------------------
// f32 -> bf16 convert
// ---------------------------------------------------------------------------
__global__ __launch_bounds__(256) void cvt16(
    const float* __restrict__ in, bf16* __restrict__ out, size_t n)
{
    size_t i = (size_t)blockIdx.x * 256 + threadIdx.x;
    if (i < n) out[i] = (bf16)in[i];
}

// ---------------------------------------------------------------------------
// A_g cols 400..927: [hs | 0-pad], bf16
// ---------------------------------------------------------------------------
__global__ __launch_bounds__(256) void ag_fill(
    const float* __restrict__ hs, bf16* __restrict__ A_g)
{
    size_t idx = (size_t)blockIdx.x * 256 + threadIdx.x;
    if (idx >= (size_t)BFULL * U6 * 528) return;
    int c = (int)(idx % 528);
    size_t bu = idx / 528;
    float v = (c < 512) ? hs[bu * 512 + c] : 0.f;
    A_g[bu * 928 + 400 + c] = (bf16)v;
}

// ---------------------------------------------------------------------------
// bf16 MFMA GEMM: C[row][n] = sum_k A[row][k] * B[n][k]
// 128x128 tile, BK=32, 4 waves (2x2), each wave 64x64 = 4x4 16x16 frags.
// EPI 0: f32 C.  EPI 1: Wo epilogue (out_hs = mask ? acc+hbg : hs_in).
// EPI 2: v0->A_g epilogue (out_hs=(bf16*)A_g, hs_in=coef, hbg=bv).
// EPI 3: bf16 C.
// ---------------------------------------------------------------------------
template <int EPI>
__global__ __launch_bounds__(256) void gemm_mfma(
    const bf16* __restrict__ A, int lda, long sAu,
    const bf16* __restrict__ B, long sBu,
    float* __restrict__ C, int ldc, long sCu,
    int K,
    const float* __restrict__ maskf, const float* __restrict__ hbg,
    const float* __restrict__ hs_in, float* __restrict__ out_hs, int b0)
{
    __shared__ bf16 Abuf[128 * 32];
    __shared__ bf16 Bbuf[128 * 32];
    const int t = threadIdx.x;
    const int lane = t & 63;
    const int wid = t >> 6;
    const int wr = wid >> 1, wc = wid & 1;
    const int brow0 = blockIdx.x * 128;
    const int c0 = blockIdx.y * 128;
    const int u = blockIdx.z;
    A += (size_t)u * sAu;
    B += (size_t)u * sBu;

    const int r0 = t >> 2, s0 = t & 3;
    const int r1 = r0 + 64;
    const int lo0 = r0 * 32 + ((s0 ^ ((r0 >> 1) & 3)) << 3);
    const int lo1 = r1 * 32 + ((s0 ^ ((r1 >> 1) & 3)) << 3);

    const bf16* Ap0 = A + (size_t)(brow0 + r0) * lda + s0 * 8;
    const bf16* Ap1 = A + (size_t)(brow0 + r1) * lda + s0 * 8;
    const bf16* Bp0 = B + (size_t)(c0 + r0) * K + s0 * 8;
    const bf16* Bp1 = B + (size_t)(c0 + r1) * K + s0 * 8;

    f32x4 acc[4][4];
#pragma unroll
    for (int m = 0; m < 4; ++m)
#pragma unroll
        for (int n = 0; n < 4; ++n) {
            f32x4 z = {0.f, 0.f, 0.f, 0.f};
            acc[m][n] = z;
        }

    const int nk = K >> 5;
    uint4 pa0 = *(const uint4*)(Ap0);
    uint4 pa1 = *(const uint4*)(Ap1);
    uint4 pb0 = *(const uint4*)(Bp0);
    uint4 pb1 = *(const uint4*)(Bp1);

    const int kg = lane >> 4;
    const int lr = lane & 15;

    for (int ks = 0; ks < nk; ++ks) {
        uint4 ca0 = pa0, ca1 = pa1, cb0 = pb0, cb1 = pb1;
        if (ks + 1 < nk) {
            const int kk = (ks + 1) << 5;
            pa0 = *(const uint4*)(Ap0 + kk);
            pa1 = *(const uint4*)(Ap1 + kk);
            pb0 = *(const uint4*)(Bp0 + kk);
            pb1 = *(const uint4*)(Bp1 + kk);
        }
        __syncthreads();
        *(uint4*)&Abuf[lo0] = ca0;
        *(uint4*)&Abuf[lo1] = ca1;
        *(uint4*)&Bbuf[lo0] = cb0;
        *(uint4*)&Bbuf[lo1] = cb1;
        __syncthreads();

        bf16x8 af[4], bfr[4];
#pragma unroll
        for (int m = 0; m < 4; ++m) {
            const int row = wr * 64 + m * 16 + lr;
            af[m] = *(bf16x8*)&Abuf[row * 32 + ((kg ^ ((row >> 1) & 3)) << 3)];
            const int col = wc * 64 + m * 16 + lr;
            bfr[m] = *(bf16x8*)&Bbuf[col * 32 + ((kg ^ ((col >> 1) & 3)) << 3)];
        }
#pragma unroll
        for (int m = 0; m < 4; ++m)
#pragma unroll
            for (int n = 0; n < 4; ++n)
                acc[m][n] = __builtin_amdgcn_mfma_f32_16x16x32_bf16(af[m], bfr[n], acc[m][n], 0, 0, 0);
    }

    // epilogue: C/D layout col = lane&15, row = (lane>>4)*4 + r
#pragma unroll
    for (int m = 0; m < 4; ++m) {
#pragma unroll
        for (int n = 0; n < 4; ++n) {
#pragma unroll
            for (int r = 0; r < 4; ++r) {
                const int row = brow0 + wr * 64 + m * 16 + kg * 4 + r;
                const int col = c0 + wc * 64 + n * 16 + lr;
                const float v = acc[m][n][r];
                if (EPI == 0) {
                    C[(size_t)u * sCu + (size_t)row * ldc + col] = v;
                } else if (EPI == 3) {
                    ((bf16*)C)[(size_t)u * sCu + (size_t)row * ldc + col] = (bf16)v;
                } else if (EPI == 1) {
                    const float mv = maskf[row * U6 + u];
                    const size_t go = ((size_t)(b0 + row) * U6 + u) * 512 + col;
                    out_hs[go] = (mv != 0.f)
                        ? v + hbg[(size_t)row * 3072 + u * 512 + col]
                        : hs_in[go];
                } else if (EPI == 2) {
                    // out_hs=(bf16*)A_g, hs_in=coef, hbg=bv
                    if (col < 400) {
                        bf16* ag = (bf16*)out_hs;
                        const float bvc = hbg[col];
#pragma unroll
                        for (int uu = 0; uu < U6; ++uu) {
                            const float cf = hs_in[row * U6 + uu];
                            const float mf = maskf[row * U6 + uu];
                            ag[((size_t)row * U6 + uu) * 928 + col] = (bf16)(cf * v + mf * bvc);
                        }
                    }
                }
            }
        }
    }
}

// ---------------------------------------------------------------------------
// LSTM elementwise: gates -> c_new, h_bg (f32 + bf16); cs_out direct to d_out
// ---------------------------------------------------------------------------
__global__ __launch_bounds__(256) void lstm_kernel(
    const float* __restrict__ gates, const float* __restrict__ b_ih,
    const float* __restrict__ b_hh, const float* __restrict__ cs,
    const float* __restrict__ maskf, float* __restrict__ h_bg,
    bf16* __restrict__ h16, float* __restrict__ cs_out, int b0, int n)
{
    int idx = blockIdx.x * 256 + threadIdx.x;
    if (idx >= n) return;
    int bl = idx / 3072;
    int r = idx - bl * 3072;
    int u = r >> 9, h = r & 511;
    const float* g = gates + (size_t)bl * 12288 + u * 2048;
    int gb = u * 2048;
    float i_ = g[h]        + b_ih[gb + h]        + b_hh[gb + h];
    float f_ = g[512 + h]  + b_ih[gb + 512 + h]  + b_hh[gb + 512 + h];
    float g_ = g[1024 + h] + b_ih[gb + 1024 + h] + b_hh[gb + 1024 + h];
    float o_ = g[1536 + h] + b_ih[gb + 1536 + h] + b_hh[gb + 1536 + h];
    float c = cs[((size_t)(b0 + bl) * U6 + u) * 512 + h];
    float cn = sigmoidf_(f_) * c + sigmoidf_(i_) * tanhf(g_);
    float hv = sigmoidf_(o_) * tanhf(cn);
    h_bg[idx] = hv;
    h16[idx] = (bf16)hv;
    float m = maskf[bl * U6 + u];
    cs_out[((size_t)(b0 + bl) * U6 + u) * 512 + h] = (m != 0.f) ? cn : c;
}

// ---------------------------------------------------------------------------
// tiny attention over bf16 qkv: qkv[bl][u*2304 + (q:128|k:128|v:2048)],
// per-batch row stride 13824. ctx written in bf16.
// ---------------------------------------------------------------------------
__global__ __launch_bounds__(256) void attn_kernel(
    const bf16* __restrict__ qkv, bf16* __restrict__ ctx)
{
    const int bl = blockIdx.x, hh = blockIdx.y, t = threadIdx.x;
    __shared__ float qs[6][32], ks[6][32], att[6][8];
    if (t < 192) {
        int u = t >> 5, d = t & 31;
        const size_t rowb = (size_t)bl * 13824 + (size_t)u * 2304;
        qs[u][d] = (float)qkv[rowb + hh * 32 + d];
        ks[u][d] = (float)qkv[rowb + 128 + hh * 32 + d];
    }
    __syncthreads();
    if (t < 36) {
        int u = t / 6, n = t - (t / 6) * 6;
        float a = 0.f;
        for (int d = 0; d < 32; ++d) a += qs[u][d] * ks[n][d];
        att[u][n] = a * 0.17677669529663687f;  // 1/sqrt(32)
    }
    __syncthreads();
    if (t < 6) {
        float mx = att[t][0];
        for (int n = 1; n < 6; ++n) mx = fmaxf(mx, att[t][n]);
        float e[6], s = 0.f;
        for (int n = 0; n < 6; ++n) { e[n] = expf(att[t][n] - mx); s += e[n]; }
        for (int n = 0; n < 6; ++n) att[t][n] = e[n] / s;
    }
    __syncthreads();
    for (int e0 = t; e0 < 512; e0 += 256) {
        float vv[6];
#pragma unroll
        for (int n = 0; n < 6; ++n)
            vv[n] = (float)qkv[(size_t)bl * 13824 + (size_t)n * 2304 + 256 + hh * 512 + e0];
#pragma unroll
        for (int u = 0; u < 6; ++u) {
            float a = 0.f;
#pragma unroll
            for (int n = 0; n < 6; ++n) a += att[u][n] * vv[n];
            ctx[((size_t)bl * U6 + u) * 2048 + hh * 512 + e0] = (bf16)a;
        }
    }
}

// ---------------------------------------------------------------------------
extern "C" void kernel_launch(void* const* d_in, const int* in_sizes, int n_in,
                              void* d_out, int out_size, void* d_ws, size_t ws_size,
                              hipStream_t stream)
{
    const float* x     = (const float*)d_in[0];
    const float* hs    = (const float*)d_in[1];
    const float* cs    = (const float*)d_in[2];
    const float* Wk    = (const float*)d_in[3];
    const float* bk    = (const float*)d_in[4];
    const float* Wv    = (const float*)d_in[5];
    const float* bv    = (const float*)d_in[6];
    const float* Wq_in = (const float*)d_in[7];
    const float* Wq_c  = (const float*)d_in[8];
    const float* Wk_c  = (const float*)d_in[9];
    const float* Wv_c  = (const float*)d_in[10];
    const float* Wo_c  = (const float*)d_in[11];
    const float* W_ih  = (const float*)d_in[12];
    const float* W_hh  = (const float*)d_in[13];
    const float* b_ih  = (const float*)d_in[14];
    const float* b_hh  = (const float*)d_in[15];

    float* out_hs = (float*)d_out;
    float* out_cs = out_hs + (size_t)BFULL * U6 * 512;

    // ---- workspace: fixed (full-batch) part ----
    size_t off = 0;
    auto alloc = [&](size_t bytes) {
        void* p = (char*)d_ws + off;
        off = (off + bytes + 255) & ~255UL;
        return p;
    };
    bf16*  Wg    = (bf16*)alloc(6UL * 2048 * 928 * 2);      // 22.8 MB
    bf16*  Wqkv  = (bf16*)alloc(6UL * 2304 * 512 * 2);      // 14.2 MB
    bf16*  WoT   = (bf16*)alloc(6UL * 512 * 2048 * 2);      // 12.6 MB
    bf16*  WvT   = (bf16*)alloc(512UL * 512 * 2);           // 0.5 MB (N-padded)
    bf16*  x16   = (bf16*)alloc((size_t)BFULL * 512 * 2);   // 2.1 MB
    bf16*  A_g   = (bf16*)alloc((size_t)BFULL * U6 * 928 * 2); // 22.8 MB
    float* coef  = (float*)alloc((size_t)BFULL * U6 * 4);
    float* maskf = (float*)alloc((size_t)BFULL * U6 * 4);
    const size_t fixedB = off;

    // ---- chunked part: gates f32 (49152 B/row) overlaid by qkv16 (27648) +
    //      ctx16 (24576) in a 52224 B/row region; hbg f32; h16 ----
    const size_t perRow = 52224 + 12288 + 6144;
    int NC = 1;
    while (NC < 16 && fixedB + (size_t)(BFULL / NC) * perRow + 4096 > ws_size) NC *= 2;
    const int Bc = BFULL / NC;

    char*  R1    = (char*)alloc((size_t)Bc * 52224);
    float* hbg   = (float*)alloc((size_t)Bc * 12288);
    bf16*  h16   = (bf16*)alloc((size_t)Bc * 6144);

    float* gates = (float*)R1;
    bf16*  qkv16 = (bf16*)R1;
    bf16*  ctx16 = (bf16*)(R1 + (size_t)Bc * 27648);

    // ---- once per call: weight builds + front-end (full batch) ----
    {
        size_t n = 6UL * 2048 * 928;
        build_wg<<<(int)((n + 255) / 256), 256, 0, stream>>>(W_ih, W_hh, Wg);
    }
    transpose_cvt<<<dim3(4, 16, U6), 256, 0, stream>>>(Wq_c, Wqkv, 512, 128, 128, 0,
                                                       512L * 128, 2304L * 512);
    transpose_cvt<<<dim3(4, 16, U6), 256, 0, stream>>>(Wk_c, Wqkv, 512, 128, 128, 128,
                                                       512L * 128, 2304L * 512);
    transpose_cvt<<<dim3(64, 16, U6), 256, 0, stream>>>(Wv_c, Wqkv, 512, 2048, 2048, 256,
                                                        512L * 2048, 2304L * 512);
    transpose_cvt<<<dim3(16, 64, U6), 256, 0, stream>>>(Wo_c, WoT, 2048, 512, 512, 0,
                                                        2048L * 512, 512L * 2048);
    transpose_cvt<<<dim3(16, 16, 1), 256, 0, stream>>>(Wv, WvT, 512, 400, 400, 0, 0, 0);
    cvt16<<<(int)(((size_t)BFULL * 512 + 255) / 256), 256, 0, stream>>>(
        x, x16, (size_t)BFULL * 512);
    score_kernel<<<BFULL / 8, 384, 0, stream>>>(x, hs, Wk, bk, Wq_in, coef, maskf);
    // v0 = x16 @ WvT^T, fused into A_g cols 0..399 (all 6 u, coef/mask scaled)
    gemm_mfma<2><<<dim3(BFULL / 128, 4, 1), 256, 0, stream>>>(
        x16, 512, 0L, WvT, 0L, nullptr, 0, 0L, 512,
        maskf, bv, coef, (float*)A_g, 0);
    ag_fill<<<(int)(((size_t)BFULL * U6 * 528 + 255) / 256), 256, 0, stream>>>(hs, A_g);

    // ---- chunk loop ----
    for (int c = 0; c < NC; ++c) {
        const int b0 = c * Bc;
        // gates = A_g @ Wg^T   (M=Bc, N=2048, K=928)
        gemm_mfma<0><<<dim3(Bc / 128, 16, U6), 256, 0, stream>>>(
            A_g + (size_t)b0 * 5568, 5568, 928L, Wg, 2048L * 928,
            gates, 12288, 2048L, 928,
            nullptr, nullptr, nullptr, nullptr, 0);
        {
            int n = Bc * 3072;
            lstm_kernel<<<(n + 255) / 256, 256, 0, stream>>>(
                gates, b_ih, b_hh, cs, maskf + (size_t)b0 * U6, hbg, h16, out_cs, b0, n);
        }
        // qkv16 = h16 @ Wqkv^T  (M=Bc, N=2304, K=512), bf16 out over gates region
        gemm_mfma<3><<<dim3(Bc / 128, 18, U6), 256, 0, stream>>>(
            h16, 3072, 512L, Wqkv, 2304L * 512, (float*)qkv16, 13824, 2304L, 512,
            nullptr, nullptr, nullptr, nullptr, 0);
        attn_kernel<<<dim3(Bc, 4), 256, 0, stream>>>(qkv16, ctx16);
        // hs_out = mask ? ctx @ WoT^T + hbg : hs   (M=Bc, N=512, K=2048)
        gemm_mfma<1><<<dim3(Bc / 128, 4, U6), 256, 0, stream>>>(
            ctx16, 12288, 2048L, WoT, 512L * 2048, nullptr, 0, 0L, 2048,
            maskf + (size_t)b0 * U6, hbg, hs, out_hs, b0);
    }
}

// Round 6
// 575.237 us; speedup vs baseline: 3.3598x; 1.0920x over previous
//
#include <hip/hip_runtime.h>
#include <math.h>

#define U6 6
#define BFULL 2048

typedef __bf16 bf16;
typedef __bf16 bf16x8 __attribute__((ext_vector_type(8)));
typedef float f32x4 __attribute__((ext_vector_type(4)));

__device__ __forceinline__ float sigmoidf_(float x) { return 1.0f / (1.0f + expf(-x)); }

// ---------------------------------------------------------------------------
// pack Wk [512][64] -> Wk_p[kg][d][4], Wq_in [6][512][64] -> Wq_p[u][kg][d][4]
// (fp32; lets score lanes do coalesced float4 loads over k)
// ---------------------------------------------------------------------------
__global__ __launch_bounds__(256) void pack_w(
    const float* __restrict__ Wk, const float* __restrict__ Wq_in,
    float* __restrict__ Wk_p, float* __restrict__ Wq_p)
{
    int idx = blockIdx.x * 256 + threadIdx.x;
    const int per = 512 * 64;                 // 32768 per matrix
    if (idx >= 7 * per) return;
    int o = idx % per;
    int mat = idx / per;                      // 0 = Wk, 1..6 = Wq_in[u]
    int j = o & 3, d = (o >> 2) & 63, kg = o >> 8;
    int k = kg * 4 + j;
    if (mat == 0) Wk_p[o] = Wk[k * 64 + d];
    else {
        int u = mat - 1;
        Wq_p[(size_t)u * per + o] = Wq_in[((size_t)u * 512 + k) * 64 + d];
    }
}

// ---------------------------------------------------------------------------
// score v2 (fp32, full batch): k0 = x@Wk+bk, q = hs@Wq_in, s0 = q.k0/8,
// s1 = q.bk/8, top-4 mask, coef = mask*sigmoid(s0-s1).
// 4 batches/block, 384 thr = 6 waves (wave u, lane d), 512 blocks.
// ---------------------------------------------------------------------------
__global__ __launch_bounds__(384) void score2_kernel(
    const float* __restrict__ x, const float* __restrict__ hs,
    const float* __restrict__ Wk_p, const float* __restrict__ bk,
    const float* __restrict__ Wq_p,
    float* __restrict__ coef, float* __restrict__ maskf)
{
    __shared__ float xt[4][512];          // 8 KB
    __shared__ float hst[4][3072];        // 48 KB
    __shared__ float k0p[6][4][64];       // 6 KB
    __shared__ float k0f[4][64];          // 1 KB
    __shared__ float ss[4][6], s1s[4][6];
    const int t = threadIdx.x;
    const int u = t >> 6, d = t & 63;
    const int b4 = blockIdx.x * 4;

    for (int j = t; j < 4 * 128; j += 384)
        *(float4*)&xt[j >> 7][(j & 127) * 4] = *(const float4*)(x + (size_t)(b4 + (j >> 7)) * 512 + (j & 127) * 4);
    for (int j = t; j < 4 * 768; j += 384)
        *(float4*)&hst[j / 768][(j % 768) * 4] = *(const float4*)(hs + (size_t)(b4 + j / 768) * 3072 + (j % 768) * 4);
    __syncthreads();

    // q accumulation: wave u, lane d, 4 batch chains
    float qa[4] = {0.f, 0.f, 0.f, 0.f};
    const float4* wqp = (const float4*)(Wq_p + (size_t)u * 32768);
#pragma unroll 4
    for (int kg = 0; kg < 128; ++kg) {
        float4 w = wqp[kg * 64 + d];
#pragma unroll
        for (int b = 0; b < 4; ++b) {
            float4 h = *(const float4*)&hst[b][u * 512 + kg * 4];
            qa[b] += w.x * h.x + w.y * h.y + w.z * h.z + w.w * h.w;
        }
    }

    // k0 partials: wave u covers kg in [st, st+cnt)
    const int starts[6] = {0, 22, 44, 65, 86, 107};
    const int counts[6] = {22, 22, 21, 21, 21, 21};
    {
        float k0a[4] = {0.f, 0.f, 0.f, 0.f};
        const float4* wkp = (const float4*)Wk_p;
        const int st = starts[u], en = st + counts[u];
        for (int kg = st; kg < en; ++kg) {
            float4 w = wkp[kg * 64 + d];
#pragma unroll
            for (int b = 0; b < 4; ++b) {
                float4 xv = *(const float4*)&xt[b][kg * 4];
                k0a[b] += w.x * xv.x + w.y * xv.y + w.z * xv.z + w.w * xv.w;
            }
        }
#pragma unroll
        for (int b = 0; b < 4; ++b) k0p[u][b][d] = k0a[b];
    }
    __syncthreads();
    if (t < 256) {
        int b = t >> 6, dd = t & 63;
        float s = bk[dd];
#pragma unroll
        for (int uu = 0; uu < 6; ++uu) s += k0p[uu][b][dd];
        k0f[b][dd] = s;
    }
    __syncthreads();

    const float bkv = bk[d];
    float s0[4], s1[4];
#pragma unroll
    for (int b = 0; b < 4; ++b) {
        s0[b] = qa[b] * k0f[b][d];
        s1[b] = qa[b] * bkv;
    }
#pragma unroll
    for (int off = 32; off > 0; off >>= 1) {
#pragma unroll
        for (int b = 0; b < 4; ++b) {
            s0[b] += __shfl_xor(s0[b], off, 64);
            s1[b] += __shfl_xor(s1[b], off, 64);
        }
    }
    if (d == 0) {
#pragma unroll
        for (int b = 0; b < 4; ++b) { ss[b][u] = s0[b] * 0.125f; s1s[b][u] = s1[b] * 0.125f; }
    }
    __syncthreads();
    if (t < 4) {
        int bb = t;
        bool sel[6] = {false,false,false,false,false,false};
        for (int it = 0; it < 4; ++it) {              // top-4, ties -> earliest
            int best = 0; float bm = -3.4e38f;
            for (int uu = 0; uu < 6; ++uu)
                if (!sel[uu] && ss[bb][uu] > bm) { bm = ss[bb][uu]; best = uu; }
            sel[best] = true;
        }
        for (int uu = 0; uu < 6; ++uu) {
            float m = sel[uu] ? 1.f : 0.f;
            float p0 = sigmoidf_(ss[bb][uu] - s1s[bb][uu]);
            maskf[(b4 + bb) * U6 + uu] = m;
            coef[(b4 + bb) * U6 + uu]  = m * p0;
        }
    }
}

// ---------------------------------------------------------------------------
// weight prep: Wg[u][g][928] = bf16 concat(W_ih[u][g][0:400], W_hh[u][g][0:512], 0)
// ---------------------------------------------------------------------------
__global__ __launch_bounds__(256) void build_wg(
    const float* __restrict__ Wih, const float* __restrict__ Whh,
    bf16* __restrict__ Wg)
{
    size_t idx = (size_t)blockIdx.x * 256 + threadIdx.x;
    if (idx >= 6UL * 2048 * 928) return;
    int u = (int)(idx / (2048 * 928));
    int r = (int)(idx % (2048 * 928));
    int g = r / 928, k = r - g * 928;
    float v = 0.f;
    if (k < 400)      v = Wih[((size_t)u * 2048 + g) * 400 + k];
    else if (k < 912) v = Whh[((size_t)u * 2048 + g) * 512 + (k - 400)];
    Wg[idx] = (bf16)v;
}

// ---------------------------------------------------------------------------
// transpose+convert: in[u][K][Nvalid] f32 -> out[u][n0base+n][K] bf16
// ---------------------------------------------------------------------------
__global__ __launch_bounds__(256) void transpose_cvt(
    const float* __restrict__ in, bf16* __restrict__ out,
    int Kdim, int Ndim, int Nvalid, int n0base, long sInU, long sOutU)
{
    __shared__ float tile[32][33];
    const int t = threadIdx.x;
    const int c = t & 31, r8 = t >> 5;
    const int n0 = blockIdx.x * 32, k0 = blockIdx.y * 32, u = blockIdx.z;
    in  += (size_t)u * sInU;
    out += (size_t)u * sOutU;
    for (int rr = r8; rr < 32; rr += 8)
        tile[rr][c] = (n0 + c < Nvalid) ? in[(size_t)(k0 + rr) * Ndim + n0 + c] : 0.f;
    __syncthreads();
    for (int rr = r8; rr < 32; rr += 8)
        out[(size_t)(n0base + n0 + rr) * Kdim + k0 + c] = (bf16)tile[c][rr];
}

// ---------------------------------------------------------------------------
__global__ __launch_bounds__(256) void cvt16(
    const float* __restrict__ in, bf16* __restrict__ out, size_t n)
{
    size_t i = (size_t)blockIdx.x * 256 + threadIdx.x;
    if (i < n) out[i] = (bf16)in[i];
}

// ---------------------------------------------------------------------------
// A_g cols 400..927: [hs | 0-pad], bf16
// ---------------------------------------------------------------------------
__global__ __launch_bounds__(256) void ag_fill(
    const float* __restrict__ hs, bf16* __restrict__ A_g)
{
    size_t idx = (size_t)blockIdx.x * 256 + threadIdx.x;
    if (idx >= (size_t)BFULL * U6 * 528) return;
    int c = (int)(idx % 528);
    size_t bu = idx / 528;
    float v = (c < 512) ? hs[bu * 512 + c] : 0.f;
    A_g[bu * 928 + 400 + c] = (bf16)v;
}

// ---------------------------------------------------------------------------
// bf16 MFMA GEMM 128x128xBK32: C[row][n] = sum_k A[row][k] * B[n][k]
// EPI 0: f32 C.  EPI 2: v0->A_g epilogue.  EPI 3: bf16 C.
// ---------------------------------------------------------------------------
template <int EPI>
__global__ __launch_bounds__(256) void gemm_mfma(
    const bf16* __restrict__ A, int lda, long sAu,
    const bf16* __restrict__ B, long sBu,
    float* __restrict__ C, int ldc, long sCu,
    int K,
    const float* __restrict__ maskf, const float* __restrict__ hbg,
    const float* __restrict__ hs_in, float* __restrict__ out_hs, int b0)
{
    __shared__ bf16 Abuf[128 * 32];
    __shared__ bf16 Bbuf[128 * 32];
    const int t = threadIdx.x;
    const int lane = t & 63;
    const int wid = t >> 6;
    const int wr = wid >> 1, wc = wid & 1;
    const int brow0 = blockIdx.x * 128;
    const int c0 = blockIdx.y * 128;
    const int u = blockIdx.z;
    A += (size_t)u * sAu;
    B += (size_t)u * sBu;

    const int r0 = t >> 2, s0 = t & 3;
    const int r1 = r0 + 64;
    const int lo0 = r0 * 32 + ((s0 ^ ((r0 >> 1) & 3)) << 3);
    const int lo1 = r1 * 32 + ((s0 ^ ((r1 >> 1) & 3)) << 3);

    const bf16* Ap0 = A + (size_t)(brow0 + r0) * lda + s0 * 8;
    const bf16* Ap1 = A + (size_t)(brow0 + r1) * lda + s0 * 8;
    const bf16* Bp0 = B + (size_t)(c0 + r0) * K + s0 * 8;
    const bf16* Bp1 = B + (size_t)(c0 + r1) * K + s0 * 8;

    f32x4 acc[4][4];
#pragma unroll
    for (int m = 0; m < 4; ++m)
#pragma unroll
        for (int n = 0; n < 4; ++n) {
            f32x4 z = {0.f, 0.f, 0.f, 0.f};
            acc[m][n] = z;
        }

    const int nk = K >> 5;
    uint4 pa0 = *(const uint4*)(Ap0);
    uint4 pa1 = *(const uint4*)(Ap1);
    uint4 pb0 = *(const uint4*)(Bp0);
    uint4 pb1 = *(const uint4*)(Bp1);

    const int kg = lane >> 4;
    const int lr = lane & 15;

    for (int ks = 0; ks < nk; ++ks) {
        uint4 ca0 = pa0, ca1 = pa1, cb0 = pb0, cb1 = pb1;
        if (ks + 1 < nk) {
            const int kk = (ks + 1) << 5;
            pa0 = *(const uint4*)(Ap0 + kk);
            pa1 = *(const uint4*)(Ap1 + kk);
            pb0 = *(const uint4*)(Bp0 + kk);
            pb1 = *(const uint4*)(Bp1 + kk);
        }
        __syncthreads();
        *(uint4*)&Abuf[lo0] = ca0;
        *(uint4*)&Abuf[lo1] = ca1;
        *(uint4*)&Bbuf[lo0] = cb0;
        *(uint4*)&Bbuf[lo1] = cb1;
        __syncthreads();

        bf16x8 af[4], bfr[4];
#pragma unroll
        for (int m = 0; m < 4; ++m) {
            const int row = wr * 64 + m * 16 + lr;
            af[m] = *(bf16x8*)&Abuf[row * 32 + ((kg ^ ((row >> 1) & 3)) << 3)];
            const int col = wc * 64 + m * 16 + lr;
            bfr[m] = *(bf16x8*)&Bbuf[col * 32 + ((kg ^ ((col >> 1) & 3)) << 3)];
        }
#pragma unroll
        for (int m = 0; m < 4; ++m)
#pragma unroll
            for (int n = 0; n < 4; ++n)
                acc[m][n] = __builtin_amdgcn_mfma_f32_16x16x32_bf16(af[m], bfr[n], acc[m][n], 0, 0, 0);
    }

#pragma unroll
    for (int m = 0; m < 4; ++m) {
#pragma unroll
        for (int n = 0; n < 4; ++n) {
#pragma unroll
            for (int r = 0; r < 4; ++r) {
                const int row = brow0 + wr * 64 + m * 16 + kg * 4 + r;
                const int col = c0 + wc * 64 + n * 16 + lr;
                const float v = acc[m][n][r];
                if (EPI == 0) {
                    C[(size_t)u * sCu + (size_t)row * ldc + col] = v;
                } else if (EPI == 3) {
                    ((bf16*)C)[(size_t)u * sCu + (size_t)row * ldc + col] = (bf16)v;
                } else if (EPI == 2) {
                    // out_hs=(bf16*)A_g, hs_in=coef, hbg=bv
                    if (col < 400) {
                        bf16* ag = (bf16*)out_hs;
                        const float bvc = hbg[col];
#pragma unroll
                        for (int uu = 0; uu < U6; ++uu) {
                            const float cf = hs_in[row * U6 + uu];
                            const float mf = maskf[row * U6 + uu];
                            ag[((size_t)row * U6 + uu) * 928 + col] = (bf16)(cf * v + mf * bvc);
                        }
                    }
                }
            }
        }
    }
}

// ---------------------------------------------------------------------------
// 64x128xBK32 MFMA GEMM, Wo epilogue: out_hs = mask ? acc + h16 : hs_in.
// 4 waves (2x2), wave tile 32x64 = 2x4 frags. Grid (M/64, N/128, 6).
// ---------------------------------------------------------------------------
__global__ __launch_bounds__(256) void gemm_m64_wo(
    const bf16* __restrict__ A, int lda,
    const bf16* __restrict__ B, long sBu, int K,
    const float* __restrict__ maskf, const bf16* __restrict__ h16,
    const float* __restrict__ hs_in, float* __restrict__ out_hs, int b0)
{
    __shared__ bf16 Abuf[64 * 32];
    __shared__ bf16 Bbuf[128 * 32];
    const int t = threadIdx.x;
    const int lane = t & 63;
    const int wid = t >> 6;
    const int wr = wid >> 1, wc = wid & 1;
    const int brow0 = blockIdx.x * 64;
    const int c0 = blockIdx.y * 128;
    const int u = blockIdx.z;
    B += (size_t)u * sBu;

    const int r0 = t >> 2, s0 = t & 3;
    const int r1 = r0 + 64;
    const int loA  = r0 * 32 + ((s0 ^ ((r0 >> 1) & 3)) << 3);
    const int loB0 = loA;
    const int loB1 = r1 * 32 + ((s0 ^ ((r1 >> 1) & 3)) << 3);

    const bf16* Ap  = A + (size_t)(brow0 + r0) * lda + s0 * 8;
    const bf16* Bp0 = B + (size_t)(c0 + r0) * K + s0 * 8;
    const bf16* Bp1 = B + (size_t)(c0 + r1) * K + s0 * 8;

    f32x4 acc[2][4];
#pragma unroll
    for (int m = 0; m < 2; ++m)
#pragma unroll
        for (int n = 0; n < 4; ++n) {
            f32x4 z = {0.f, 0.f, 0.f, 0.f};
            acc[m][n] = z;
        }

    const int nk = K >> 5;
    uint4 pa  = *(const uint4*)(Ap);
    uint4 pb0 = *(const uint4*)(Bp0);
    uint4 pb1 = *(const uint4*)(Bp1);

    const int kg = lane >> 4;
    const int lr = lane & 15;

    for (int ks = 0; ks < nk; ++ks) {
        uint4 ca = pa, cb0 = pb0, cb1 = pb1;
        if (ks + 1 < nk) {
            const int kk = (ks + 1) << 5;
            pa  = *(const uint4*)(Ap + kk);
            pb0 = *(const uint4*)(Bp0 + kk);
            pb1 = *(const uint4*)(Bp1 + kk);
        }
        __syncthreads();
        *(uint4*)&Abuf[loA]  = ca;
        *(uint4*)&Bbuf[loB0] = cb0;
        *(uint4*)&Bbuf[loB1] = cb1;
        __syncthreads();

        bf16x8 af[2], bfr[4];
#pragma unroll
        for (int m = 0; m < 2; ++m) {
            const int row = wr * 32 + m * 16 + lr;
            af[m] = *(bf16x8*)&Abuf[row * 32 + ((kg ^ ((row >> 1) & 3)) << 3)];
        }
#pragma unroll
        for (int n = 0; n < 4; ++n) {
            const int col = wc * 64 + n * 16 + lr;
            bfr[n] = *(bf16x8*)&Bbuf[col * 32 + ((kg ^ ((col >> 1) & 3)) << 3)];
        }
#pragma unroll
        for (int m = 0; m < 2; ++m)
#pragma unroll
            for (int n = 0; n < 4; ++n)
                acc[m][n] = __builtin_amdgcn_mfma_f32_16x16x32_bf16(af[m], bfr[n], acc[m][n], 0, 0, 0);
    }

#pragma unroll
    for (int m = 0; m < 2; ++m) {
#pragma unroll
        for (int n = 0; n < 4; ++n) {
#pragma unroll
            for (int r = 0; r < 4; ++r) {
                const int row = brow0 + wr * 32 + m * 16 + kg * 4 + r;
                const int col = c0 + wc * 64 + n * 16 + lr;
                const float mv = maskf[row * U6 + u];
                const size_t go = ((size_t)(b0 + row) * U6 + u) * 512 + col;
                out_hs[go] = (mv != 0.f)
                    ? acc[m][n][r] + (float)h16[(size_t)row * 3072 + u * 512 + col]
                    : hs_in[go];
            }
        }
    }
}

// ---------------------------------------------------------------------------
// LSTM elementwise: gates -> c_new, h16 (bf16); cs_out direct to d_out
// ---------------------------------------------------------------------------
__global__ __launch_bounds__(256) void lstm_kernel(
    const float* __restrict__ gates, const float* __restrict__ b_ih,
    const float* __restrict__ b_hh, const float* __restrict__ cs,
    const float* __restrict__ maskf,
    bf16* __restrict__ h16, float* __restrict__ cs_out, int b0, int n)
{
    int idx = blockIdx.x * 256 + threadIdx.x;
    if (idx >= n) return;
    int bl = idx / 3072;
    int r = idx - bl * 3072;
    int u = r >> 9, h = r & 511;
    const float* g = gates + (size_t)bl * 12288 + u * 2048;
    int gb = u * 2048;
    float i_ = g[h]        + b_ih[gb + h]        + b_hh[gb + h];
    float f_ = g[512 + h]  + b_ih[gb + 512 + h]  + b_hh[gb + 512 + h];
    float g_ = g[1024 + h] + b_ih[gb + 1024 + h] + b_hh[gb + 1024 + h];
    float o_ = g[1536 + h] + b_ih[gb + 1536 + h] + b_hh[gb + 1536 + h];
    float c = cs[((size_t)(b0 + bl) * U6 + u) * 512 + h];
    float cn = sigmoidf_(f_) * c + sigmoidf_(i_) * tanhf(g_);
    float hv = sigmoidf_(o_) * tanhf(cn);
    h16[idx] = (bf16)hv;
    float m = maskf[bl * U6 + u];
    cs_out[((size_t)(b0 + bl) * U6 + u) * 512 + h] = (m != 0.f) ? cn : c;
}

// ---------------------------------------------------------------------------
// tiny attention over bf16 qkv: qkv[bl][u*2304 + (q:128|k:128|v:2048)],
// per-batch row stride 13824. ctx written in bf16.
// ---------------------------------------------------------------------------
__global__ __launch_bounds__(256) void attn_kernel(
    const bf16* __restrict__ qkv, bf16* __restrict__ ctx)
{
    const int bl = blockIdx.x, hh = blockIdx.y, t = threadIdx.x;
    __shared__ float qs[6][32], ks[6][32], att[6][8];
    if (t < 192) {
        int u = t >> 5, d = t & 31;
        const size_t rowb = (size_t)bl * 13824 + (size_t)u * 2304;
        qs[u][d] = (float)qkv[rowb + hh * 32 + d];
        ks[u][d] = (float)qkv[rowb + 128 + hh * 32 + d];
    }
    __syncthreads();
    if (t < 36) {
        int u = t / 6, n = t - (t / 6) * 6;
        float a = 0.f;
        for (int d = 0; d < 32; ++d) a += qs[u][d] * ks[n][d];
        att[u][n] = a * 0.17677669529663687f;  // 1/sqrt(32)
    }
    __syncthreads();
    if (t < 6) {
        float mx = att[t][0];
        for (int n = 1; n < 6; ++n) mx = fmaxf(mx, att[t][n]);
        float e[6], s = 0.f;
        for (int n = 0; n < 6; ++n) { e[n] = expf(att[t][n] - mx); s += e[n]; }
        for (int n = 0; n < 6; ++n) att[t][n] = e[n] / s;
    }
    __syncthreads();
    for (int e0 = t; e0 < 512; e0 += 256) {
        float vv[6];
#pragma unroll
        for (int n = 0; n < 6; ++n)
            vv[n] = (float)qkv[(size_t)bl * 13824 + (size_t)n * 2304 + 256 + hh * 512 + e0];
#pragma unroll
        for (int u = 0; u < 6; ++u) {
            float a = 0.f;
#pragma unroll
            for (int n = 0; n < 6; ++n) a += att[u][n] * vv[n];
            ctx[((size_t)bl * U6 + u) * 2048 + hh * 512 + e0] = (bf16)a;
        }
    }
}

// ---------------------------------------------------------------------------
extern "C" void kernel_launch(void* const* d_in, const int* in_sizes, int n_in,
                              void* d_out, int out_size, void* d_ws, size_t ws_size,
                              hipStream_t stream)
{
    const float* x     = (const float*)d_in[0];
    const float* hs    = (const float*)d_in[1];
    const float* cs    = (const float*)d_in[2];
    const float* Wk    = (const float*)d_in[3];
    const float* bk    = (const float*)d_in[4];
    const float* Wv    = (const float*)d_in[5];
    const float* bv    = (const float*)d_in[6];
    const float* Wq_in = (const float*)d_in[7];
    const float* Wq_c  = (const float*)d_in[8];
    const float* Wk_c  = (const float*)d_in[9];
    const float* Wv_c  = (const float*)d_in[10];
    const float* Wo_c  = (const float*)d_in[11];
    const float* W_ih  = (const float*)d_in[12];
    const float* W_hh  = (const float*)d_in[13];
    const float* b_ih  = (const float*)d_in[14];
    const float* b_hh  = (const float*)d_in[15];

    float* out_hs = (float*)d_out;
    float* out_cs = out_hs + (size_t)BFULL * U6 * 512;

    // ---- workspace: fixed (full-batch) part ----
    size_t off = 0;
    auto alloc = [&](size_t bytes) {
        void* p = (char*)d_ws + off;
        off = (off + bytes + 255) & ~255UL;
        return p;
    };
    bf16*  Wg    = (bf16*)alloc(6UL * 2048 * 928 * 2);       // 22.8 MB
    bf16*  Wqkv  = (bf16*)alloc(6UL * 2304 * 512 * 2);       // 14.2 MB
    bf16*  WoT   = (bf16*)alloc(6UL * 512 * 2048 * 2);       // 12.6 MB
    bf16*  WvT   = (bf16*)alloc(512UL * 512 * 2);            // 0.5 MB
    bf16*  x16   = (bf16*)alloc((size_t)BFULL * 512 * 2);    // 2.1 MB
    bf16*  A_g   = (bf16*)alloc((size_t)BFULL * U6 * 928 * 2); // 22.8 MB
    float* Wk_p  = (float*)alloc(512UL * 64 * 4);            // 0.13 MB
    float* Wq_p  = (float*)alloc(6UL * 512 * 64 * 4);        // 0.79 MB
    float* coef  = (float*)alloc((size_t)BFULL * U6 * 4);
    float* maskf = (float*)alloc((size_t)BFULL * U6 * 4);
    const size_t fixedB = off;

    // ---- chunked part: gates f32 (49152 B/row) overlaid by qkv16 (27648) +
    //      ctx16 (24576) in a 52224 B/row region; h16 bf16 ----
    const size_t perRow = 52224 + 6144;
    int NC = 1;
    while (NC < 16 && fixedB + (size_t)(BFULL / NC) * perRow + 4096 > ws_size) NC *= 2;
    const int Bc = BFULL / NC;

    char*  R1    = (char*)alloc((size_t)Bc * 52224);
    bf16*  h16   = (bf16*)alloc((size_t)Bc * 6144);

    float* gates = (float*)R1;
    bf16*  qkv16 = (bf16*)R1;
    bf16*  ctx16 = (bf16*)(R1 + (size_t)Bc * 27648);

    // ---- once per call: weight builds + front-end (full batch) ----
    {
        size_t n = 6UL * 2048 * 928;
        build_wg<<<(int)((n + 255) / 256), 256, 0, stream>>>(W_ih, W_hh, Wg);
    }
    transpose_cvt<<<dim3(4, 16, U6), 256, 0, stream>>>(Wq_c, Wqkv, 512, 128, 128, 0,
                                                       512L * 128, 2304L * 512);
    transpose_cvt<<<dim3(4, 16, U6), 256, 0, stream>>>(Wk_c, Wqkv, 512, 128, 128, 128,
                                                       512L * 128, 2304L * 512);
    transpose_cvt<<<dim3(64, 16, U6), 256, 0, stream>>>(Wv_c, Wqkv, 512, 2048, 2048, 256,
                                                        512L * 2048, 2304L * 512);
    transpose_cvt<<<dim3(16, 64, U6), 256, 0, stream>>>(Wo_c, WoT, 2048, 512, 512, 0,
                                                        2048L * 512, 512L * 2048);
    transpose_cvt<<<dim3(16, 16, 1), 256, 0, stream>>>(Wv, WvT, 512, 400, 400, 0, 0, 0);
    pack_w<<<(7 * 512 * 64 + 255) / 256, 256, 0, stream>>>(Wk, Wq_in, Wk_p, Wq_p);
    cvt16<<<(int)(((size_t)BFULL * 512 + 255) / 256), 256, 0, stream>>>(
        x, x16, (size_t)BFULL * 512);
    score2_kernel<<<BFULL / 4, 384, 0, stream>>>(x, hs, Wk_p, bk, Wq_p, coef, maskf);
    // v0 = x16 @ WvT^T, fused into A_g cols 0..399 (all 6 u, coef/mask scaled)
    gemm_mfma<2><<<dim3(BFULL / 128, 4, 1), 256, 0, stream>>>(
        x16, 512, 0L, WvT, 0L, nullptr, 0, 0L, 512,
        maskf, bv, coef, (float*)A_g, 0);
    ag_fill<<<(int)(((size_t)BFULL * U6 * 528 + 255) / 256), 256, 0, stream>>>(hs, A_g);

    // ---- chunk loop ----
    for (int c = 0; c < NC; ++c) {
        const int b0 = c * Bc;
        // gates = A_g @ Wg^T   (M=Bc, N=2048, K=928)
        gemm_mfma<0><<<dim3(Bc / 128, 16, U6), 256, 0, stream>>>(
            A_g + (size_t)b0 * 5568, 5568, 928L, Wg, 2048L * 928,
            gates, 12288, 2048L, 928,
            nullptr, nullptr, nullptr, nullptr, 0);
        {
            int n = Bc * 3072;
            lstm_kernel<<<(n + 255) / 256, 256, 0, stream>>>(
                gates, b_ih, b_hh, cs, maskf + (size_t)b0 * U6, h16, out_cs, b0, n);
        }
        // qkv16 = h16 @ Wqkv^T  (M=Bc, N=2304, K=512), bf16 out over gates region
        gemm_mfma<3><<<dim3(Bc / 128, 18, U6), 256, 0, stream>>>(
            h16, 3072, 512L, Wqkv, 2304L * 512, (float*)qkv16, 13824, 2304L, 512,
            nullptr, nullptr, nullptr, nullptr, 0);
        attn_kernel<<<dim3(Bc, 4), 256, 0, stream>>>(qkv16, ctx16);
        // hs_out = mask ? ctx @ WoT^T + h16 : hs   (M=Bc, N=512, K=2048)
        gemm_m64_wo<<<dim3(Bc / 64, 4, U6), 256, 0, stream>>>(
            ctx16, 2048, WoT, 512L * 2048, 2048,
            maskf + (size_t)b0 * U6, h16, hs, out_hs, b0);
    }
}

// Round 7
// 545.838 us; speedup vs baseline: 3.5408x; 1.0539x over previous
//
#include <hip/hip_runtime.h>
#include <math.h>

#define U6 6
#define BFULL 2048

typedef __bf16 bf16;
typedef __bf16 bf16x8 __attribute__((ext_vector_type(8)));
typedef float f32x4 __attribute__((ext_vector_type(4)));

__device__ __forceinline__ float sigmoidf_(float x) { return 1.0f / (1.0f + expf(-x)); }

// XCD-aware bijective block swizzle (T1): contiguous logical chunk per XCD.
__device__ __forceinline__ void swz_block(int& bx, int& by, int& bz) {
    const int nx = gridDim.x, ny = gridDim.y, nz = gridDim.z;
    const int nwg = nx * ny * nz;
    int lin = blockIdx.x + nx * (blockIdx.y + ny * blockIdx.z);
    if ((nwg & 7) == 0) {
        const int cpx = nwg >> 3;
        lin = (lin & 7) * cpx + (lin >> 3);
    }
    bx = lin % nx; int tq = lin / nx; by = tq % ny; bz = tq / ny;
}

// ---------------------------------------------------------------------------
// pack Wk [512][64] -> Wk_p[kg][d][4], Wq_in [6][512][64] -> Wq_p[u][kg][d][4]
// ---------------------------------------------------------------------------
__global__ __launch_bounds__(256) void pack_w(
    const float* __restrict__ Wk, const float* __restrict__ Wq_in,
    float* __restrict__ Wk_p, float* __restrict__ Wq_p)
{
    int idx = blockIdx.x * 256 + threadIdx.x;
    const int per = 512 * 64;
    if (idx >= 7 * per) return;
    int o = idx % per;
    int mat = idx / per;
    int j = o & 3, d = (o >> 2) & 63, kg = o >> 8;
    int k = kg * 4 + j;
    if (mat == 0) Wk_p[o] = Wk[k * 64 + d];
    else {
        int u = mat - 1;
        Wq_p[(size_t)u * per + o] = Wq_in[((size_t)u * 512 + k) * 64 + d];
    }
}

// ---------------------------------------------------------------------------
// score v2 (fp32, full batch): top-4 mask + coef. 4 batches/block, 6 waves.
// ---------------------------------------------------------------------------
__global__ __launch_bounds__(384) void score2_kernel(
    const float* __restrict__ x, const float* __restrict__ hs,
    const float* __restrict__ Wk_p, const float* __restrict__ bk,
    const float* __restrict__ Wq_p,
    float* __restrict__ coef, float* __restrict__ maskf)
{
    __shared__ float xt[4][512];
    __shared__ float hst[4][3072];
    __shared__ float k0p[6][4][64];
    __shared__ float k0f[4][64];
    __shared__ float ss[4][6], s1s[4][6];
    const int t = threadIdx.x;
    const int u = t >> 6, d = t & 63;
    const int b4 = blockIdx.x * 4;

    for (int j = t; j < 4 * 128; j += 384)
        *(float4*)&xt[j >> 7][(j & 127) * 4] = *(const float4*)(x + (size_t)(b4 + (j >> 7)) * 512 + (j & 127) * 4);
    for (int j = t; j < 4 * 768; j += 384)
        *(float4*)&hst[j / 768][(j % 768) * 4] = *(const float4*)(hs + (size_t)(b4 + j / 768) * 3072 + (j % 768) * 4);
    __syncthreads();

    float qa[4] = {0.f, 0.f, 0.f, 0.f};
    const float4* wqp = (const float4*)(Wq_p + (size_t)u * 32768);
#pragma unroll 4
    for (int kg = 0; kg < 128; ++kg) {
        float4 w = wqp[kg * 64 + d];
#pragma unroll
        for (int b = 0; b < 4; ++b) {
            float4 h = *(const float4*)&hst[b][u * 512 + kg * 4];
            qa[b] += w.x * h.x + w.y * h.y + w.z * h.z + w.w * h.w;
        }
    }

    const int starts[6] = {0, 22, 44, 65, 86, 107};
    const int counts[6] = {22, 22, 21, 21, 21, 21};
    {
        float k0a[4] = {0.f, 0.f, 0.f, 0.f};
        const float4* wkp = (const float4*)Wk_p;
        const int st = starts[u], en = st + counts[u];
        for (int kg = st; kg < en; ++kg) {
            float4 w = wkp[kg * 64 + d];
#pragma unroll
            for (int b = 0; b < 4; ++b) {
                float4 xv = *(const float4*)&xt[b][kg * 4];
                k0a[b] += w.x * xv.x + w.y * xv.y + w.z * xv.z + w.w * xv.w;
            }
        }
#pragma unroll
        for (int b = 0; b < 4; ++b) k0p[u][b][d] = k0a[b];
    }
    __syncthreads();
    if (t < 256) {
        int b = t >> 6, dd = t & 63;
        float s = bk[dd];
#pragma unroll
        for (int uu = 0; uu < 6; ++uu) s += k0p[uu][b][dd];
        k0f[b][dd] = s;
    }
    __syncthreads();

    const float bkv = bk[d];
    float s0[4], s1[4];
#pragma unroll
    for (int b = 0; b < 4; ++b) {
        s0[b] = qa[b] * k0f[b][d];
        s1[b] = qa[b] * bkv;
    }
#pragma unroll
    for (int off = 32; off > 0; off >>= 1) {
#pragma unroll
        for (int b = 0; b < 4; ++b) {
            s0[b] += __shfl_xor(s0[b], off, 64);
            s1[b] += __shfl_xor(s1[b], off, 64);
        }
    }
    if (d == 0) {
#pragma unroll
        for (int b = 0; b < 4; ++b) { ss[b][u] = s0[b] * 0.125f; s1s[b][u] = s1[b] * 0.125f; }
    }
    __syncthreads();
    if (t < 4) {
        int bb = t;
        bool sel[6] = {false,false,false,false,false,false};
        for (int it = 0; it < 4; ++it) {
            int best = 0; float bm = -3.4e38f;
            for (int uu = 0; uu < 6; ++uu)
                if (!sel[uu] && ss[bb][uu] > bm) { bm = ss[bb][uu]; best = uu; }
            sel[best] = true;
        }
        for (int uu = 0; uu < 6; ++uu) {
            float m = sel[uu] ? 1.f : 0.f;
            float p0 = sigmoidf_(ss[bb][uu] - s1s[bb][uu]);
            maskf[(b4 + bb) * U6 + uu] = m;
            coef[(b4 + bb) * U6 + uu]  = m * p0;
        }
    }
}

// ---------------------------------------------------------------------------
// weight prep, GATE-INTERLEAVED: Wg[u][n=h*4+gate][k] with
// k<400: W_ih[u][gate*512+h][k]; 400<=k<912: W_hh[...][k-400];
// k==912: b_ih+b_hh (bias slot; A_g col 912 = 1.0); else 0.
// ---------------------------------------------------------------------------
__global__ __launch_bounds__(256) void build_wg(
    const float* __restrict__ Wih, const float* __restrict__ Whh,
    const float* __restrict__ bih, const float* __restrict__ bhh,
    bf16* __restrict__ Wg)
{
    size_t idx = (size_t)blockIdx.x * 256 + threadIdx.x;
    if (idx >= 6UL * 2048 * 928) return;
    int u = (int)(idx / (2048 * 928));
    int r = (int)(idx % (2048 * 928));
    int gp = r / 928, k = r - gp * 928;
    int h = gp >> 2, gate = gp & 3;
    int gsrc = gate * 512 + h;
    float v = 0.f;
    if (k < 400)       v = Wih[((size_t)u * 2048 + gsrc) * 400 + k];
    else if (k < 912)  v = Whh[((size_t)u * 2048 + gsrc) * 512 + (k - 400)];
    else if (k == 912) v = bih[(size_t)u * 2048 + gsrc] + bhh[(size_t)u * 2048 + gsrc];
    Wg[idx] = (bf16)v;
}

// ---------------------------------------------------------------------------
// transpose+convert: in[u][K][Nvalid] f32 -> out[u][n0base+n][K] bf16
// ---------------------------------------------------------------------------
__global__ __launch_bounds__(256) void transpose_cvt(
    const float* __restrict__ in, bf16* __restrict__ out,
    int Kdim, int Ndim, int Nvalid, int n0base, long sInU, long sOutU)
{
    __shared__ float tile[32][33];
    const int t = threadIdx.x;
    const int c = t & 31, r8 = t >> 5;
    const int n0 = blockIdx.x * 32, k0 = blockIdx.y * 32, u = blockIdx.z;
    in  += (size_t)u * sInU;
    out += (size_t)u * sOutU;
    for (int rr = r8; rr < 32; rr += 8)
        tile[rr][c] = (n0 + c < Nvalid) ? in[(size_t)(k0 + rr) * Ndim + n0 + c] : 0.f;
    __syncthreads();
    for (int rr = r8; rr < 32; rr += 8)
        out[(size_t)(n0base + n0 + rr) * Kdim + k0 + c] = (bf16)tile[c][rr];
}

// ---------------------------------------------------------------------------
__global__ __launch_bounds__(256) void cvt16(
    const float* __restrict__ in, bf16* __restrict__ out, size_t n)
{
    size_t i = (size_t)blockIdx.x * 256 + threadIdx.x;
    if (i < n) out[i] = (bf16)in[i];
}

// ---------------------------------------------------------------------------
// A_g cols 400..927: [hs | 1.0 @ col 912 | 0-pad], bf16
// ---------------------------------------------------------------------------
__global__ __launch_bounds__(256) void ag_fill(
    const float* __restrict__ hs, bf16* __restrict__ A_g)
{
    size_t idx = (size_t)blockIdx.x * 256 + threadIdx.x;
    if (idx >= (size_t)BFULL * U6 * 528) return;
    int c = (int)(idx % 528);
    size_t bu = idx / 528;
    float v = (c < 512) ? hs[bu * 512 + c] : ((c == 512) ? 1.0f : 0.f);
    A_g[bu * 928 + 400 + c] = (bf16)v;
}

// ---------------------------------------------------------------------------
// bf16 MFMA GEMM 128x128xBK32: C[row][n] = sum_k A[row][k] * B[n][k]
// EPI 2: v0->A_g epilogue.  EPI 3: bf16 C.
// ---------------------------------------------------------------------------
template <int EPI>
__global__ __launch_bounds__(256) void gemm_mfma(
    const bf16* __restrict__ A, int lda, long sAu,
    const bf16* __restrict__ B, long sBu,
    float* __restrict__ C, int ldc, long sCu,
    int K,
    const float* __restrict__ maskf, const float* __restrict__ hbg,
    const float* __restrict__ hs_in, float* __restrict__ out_hs, int b0)
{
    __shared__ bf16 Abuf[128 * 32];
    __shared__ bf16 Bbuf[128 * 32];
    int bxi, byi, bzi;
    swz_block(bxi, byi, bzi);
    const int t = threadIdx.x;
    const int lane = t & 63;
    const int wid = t >> 6;
    const int wr = wid >> 1, wc = wid & 1;
    const int brow0 = bxi * 128;
    const int c0 = byi * 128;
    const int u = bzi;
    A += (size_t)u * sAu;
    B += (size_t)u * sBu;

    const int r0 = t >> 2, s0 = t & 3;
    const int r1 = r0 + 64;
    const int lo0 = r0 * 32 + ((s0 ^ ((r0 >> 1) & 3)) << 3);
    const int lo1 = r1 * 32 + ((s0 ^ ((r1 >> 1) & 3)) << 3);

    const bf16* Ap0 = A + (size_t)(brow0 + r0) * lda + s0 * 8;
    const bf16* Ap1 = A + (size_t)(brow0 + r1) * lda + s0 * 8;
    const bf16* Bp0 = B + (size_t)(c0 + r0) * K + s0 * 8;
    const bf16* Bp1 = B + (size_t)(c0 + r1) * K + s0 * 8;

    f32x4 acc[4][4];
#pragma unroll
    for (int m = 0; m < 4; ++m)
#pragma unroll
        for (int n = 0; n < 4; ++n) {
            f32x4 z = {0.f, 0.f, 0.f, 0.f};
            acc[m][n] = z;
        }

    const int nk = K >> 5;
    uint4 pa0 = *(const uint4*)(Ap0);
    uint4 pa1 = *(const uint4*)(Ap1);
    uint4 pb0 = *(const uint4*)(Bp0);
    uint4 pb1 = *(const uint4*)(Bp1);

    const int kg = lane >> 4;
    const int lr = lane & 15;

    for (int ks = 0; ks < nk; ++ks) {
        uint4 ca0 = pa0, ca1 = pa1, cb0 = pb0, cb1 = pb1;
        if (ks + 1 < nk) {
            const int kk = (ks + 1) << 5;
            pa0 = *(const uint4*)(Ap0 + kk);
            pa1 = *(const uint4*)(Ap1 + kk);
            pb0 = *(const uint4*)(Bp0 + kk);
            pb1 = *(const uint4*)(Bp1 + kk);
        }
        __syncthreads();
        *(uint4*)&Abuf[lo0] = ca0;
        *(uint4*)&Abuf[lo1] = ca1;
        *(uint4*)&Bbuf[lo0] = cb0;
        *(uint4*)&Bbuf[lo1] = cb1;
        __syncthreads();

        bf16x8 af[4], bfr[4];
#pragma unroll
        for (int m = 0; m < 4; ++m) {
            const int row = wr * 64 + m * 16 + lr;
            af[m] = *(bf16x8*)&Abuf[row * 32 + ((kg ^ ((row >> 1) & 3)) << 3)];
            const int col = wc * 64 + m * 16 + lr;
            bfr[m] = *(bf16x8*)&Bbuf[col * 32 + ((kg ^ ((col >> 1) & 3)) << 3)];
        }
#pragma unroll
        for (int m = 0; m < 4; ++m)
#pragma unroll
            for (int n = 0; n < 4; ++n)
                acc[m][n] = __builtin_amdgcn_mfma_f32_16x16x32_bf16(af[m], bfr[n], acc[m][n], 0, 0, 0);
    }

#pragma unroll
    for (int m = 0; m < 4; ++m) {
#pragma unroll
        for (int n = 0; n < 4; ++n) {
#pragma unroll
            for (int r = 0; r < 4; ++r) {
                const int row = brow0 + wr * 64 + m * 16 + kg * 4 + r;
                const int col = c0 + wc * 64 + n * 16 + lr;
                const float v = acc[m][n][r];
                if (EPI == 3) {
                    ((bf16*)C)[(size_t)u * sCu + (size_t)row * ldc + col] = (bf16)v;
                } else if (EPI == 2) {
                    // out_hs=(bf16*)A_g, hs_in=coef, hbg=bv
                    if (col < 400) {
                        bf16* ag = (bf16*)out_hs;
                        const float bvc = hbg[col];
#pragma unroll
                        for (int uu = 0; uu < U6; ++uu) {
                            const float cf = hs_in[row * U6 + uu];
                            const float mf = maskf[row * U6 + uu];
                            ag[((size_t)row * U6 + uu) * 928 + col] = (bf16)(cf * v + mf * bvc);
                        }
                    }
                }
            }
        }
    }
}

// ---------------------------------------------------------------------------
// gates GEMM + fused LSTM epilogue. B = gate-interleaved Wg (bias in k=912).
// Epilogue per m-stripe: stage 32x128 f32 in LDS (reusing Abuf/Bbuf), then
// each thread reads one gate-quad (i,f,g,o contiguous) -> cn, hv;
// writes h16 (bf16) and cs_out (f32, direct to d_out).
// ---------------------------------------------------------------------------
__global__ __launch_bounds__(256) void gemm_gates_fused(
    const bf16* __restrict__ A,              // A_g + b0*5568, lda 5568, +u*928
    const bf16* __restrict__ Wg,             // [u][2048][928]
    const float* __restrict__ cs,            // global, (b)*6+u rows
    const float* __restrict__ maskf,         // chunk-offset (b0*6 applied)
    bf16* __restrict__ h16,                  // chunk-local [row][u*512+h]
    float* __restrict__ cs_out,              // global
    int b0)
{
    __shared__ bf16 smem[2 * 128 * 32];      // Abuf | Bbuf ; epilogue: 16 KB f32
    bf16* Abuf = smem;
    bf16* Bbuf = smem + 128 * 32;
    int bxi, byi, bzi;
    swz_block(bxi, byi, bzi);
    const int t = threadIdx.x;
    const int lane = t & 63;
    const int wid = t >> 6;
    const int wr = wid >> 1, wc = wid & 1;
    const int brow0 = bxi * 128;
    const int c0 = byi * 128;
    const int u = bzi;
    const bf16* Au = A + (size_t)u * 928;
    const bf16* Bu = Wg + (size_t)u * 2048 * 928;
    const int K = 928;

    const int r0 = t >> 2, s0 = t & 3;
    const int r1 = r0 + 64;
    const int lo0 = r0 * 32 + ((s0 ^ ((r0 >> 1) & 3)) << 3);
    const int lo1 = r1 * 32 + ((s0 ^ ((r1 >> 1) & 3)) << 3);

    const bf16* Ap0 = Au + (size_t)(brow0 + r0) * 5568 + s0 * 8;
    const bf16* Ap1 = Au + (size_t)(brow0 + r1) * 5568 + s0 * 8;
    const bf16* Bp0 = Bu + (size_t)(c0 + r0) * K + s0 * 8;
    const bf16* Bp1 = Bu + (size_t)(c0 + r1) * K + s0 * 8;

    f32x4 acc[4][4];
#pragma unroll
    for (int m = 0; m < 4; ++m)
#pragma unroll
        for (int n = 0; n < 4; ++n) {
            f32x4 z = {0.f, 0.f, 0.f, 0.f};
            acc[m][n] = z;
        }

    const int nk = K >> 5;   // 29
    uint4 pa0 = *(const uint4*)(Ap0);
    uint4 pa1 = *(const uint4*)(Ap1);
    uint4 pb0 = *(const uint4*)(Bp0);
    uint4 pb1 = *(const uint4*)(Bp1);

    const int kg = lane >> 4;
    const int lr = lane & 15;

    for (int ks = 0; ks < nk; ++ks) {
        uint4 ca0 = pa0, ca1 = pa1, cb0 = pb0, cb1 = pb1;
        if (ks + 1 < nk) {
            const int kk = (ks + 1) << 5;
            pa0 = *(const uint4*)(Ap0 + kk);
            pa1 = *(const uint4*)(Ap1 + kk);
            pb0 = *(const uint4*)(Bp0 + kk);
            pb1 = *(const uint4*)(Bp1 + kk);
        }
        __syncthreads();
        *(uint4*)&Abuf[lo0] = ca0;
        *(uint4*)&Abuf[lo1] = ca1;
        *(uint4*)&Bbuf[lo0] = cb0;
        *(uint4*)&Bbuf[lo1] = cb1;
        __syncthreads();

        bf16x8 af[4], bfr[4];
#pragma unroll
        for (int m = 0; m < 4; ++m) {
            const int row = wr * 64 + m * 16 + lr;
            af[m] = *(bf16x8*)&Abuf[row * 32 + ((kg ^ ((row >> 1) & 3)) << 3)];
            const int col = wc * 64 + m * 16 + lr;
            bfr[m] = *(bf16x8*)&Bbuf[col * 32 + ((kg ^ ((col >> 1) & 3)) << 3)];
        }
#pragma unroll
        for (int m = 0; m < 4; ++m)
#pragma unroll
            for (int n = 0; n < 4; ++n)
                acc[m][n] = __builtin_amdgcn_mfma_f32_16x16x32_bf16(af[m], bfr[n], acc[m][n], 0, 0, 0);
    }

    // fused LSTM epilogue: 4 m-stripes of 32 rows x 128 cols (=32 h-quads)
    float* st = (float*)smem;                 // 32*128 f32 = 16 KB
    const int hbase = c0 >> 2;                // 32 h per block-col-tile
#pragma unroll
    for (int m = 0; m < 4; ++m) {
        __syncthreads();                      // LDS free (prev reads done)
#pragma unroll
        for (int n = 0; n < 4; ++n) {
#pragma unroll
            for (int r = 0; r < 4; ++r) {
                const int lrow = wr * 16 + kg * 4 + r;          // 0..31
                const int col  = wc * 64 + n * 16 + lr;         // 0..127
                st[lrow * 128 + col] = acc[m][n][r];
            }
        }
        __syncthreads();
#pragma unroll
        for (int i = 0; i < 4; ++i) {
            const int p = i * 256 + t;                          // 0..1023
            const int hl = p & 31, lrow = p >> 5;
            const int grow = brow0 + (lrow >> 4) * 64 + m * 16 + (lrow & 15);
            const int hg = hbase + hl;
            const float4 g4 = *(const float4*)&st[lrow * 128 + hl * 4];
            const size_t cidx = ((size_t)(b0 + grow) * U6 + u) * 512 + hg;
            const float c = cs[cidx];
            const float cn = sigmoidf_(g4.y) * c + sigmoidf_(g4.x) * tanhf(g4.z);
            const float hv = sigmoidf_(g4.w) * tanhf(cn);
            h16[(size_t)grow * 3072 + u * 512 + hg] = (bf16)hv;
            const float mk = maskf[grow * U6 + u];
            cs_out[cidx] = (mk != 0.f) ? cn : c;
        }
    }
}

// ---------------------------------------------------------------------------
// 64x128xBK32 MFMA GEMM, Wo epilogue: out_hs = mask ? acc + h16 : hs_in.
// ---------------------------------------------------------------------------
__global__ __launch_bounds__(256) void gemm_m64_wo(
    const bf16* __restrict__ A, int lda,
    const bf16* __restrict__ B, long sBu, int K,
    const float* __restrict__ maskf, const bf16* __restrict__ h16,
    const float* __restrict__ hs_in, float* __restrict__ out_hs, int b0)
{
    __shared__ bf16 Abuf[64 * 32];
    __shared__ bf16 Bbuf[128 * 32];
    int bxi, byi, bzi;
    swz_block(bxi, byi, bzi);
    const int t = threadIdx.x;
    const int lane = t & 63;
    const int wid = t >> 6;
    const int wr = wid >> 1, wc = wid & 1;
    const int brow0 = bxi * 64;
    const int c0 = byi * 128;
    const int u = bzi;
    B += (size_t)u * sBu;

    const int r0 = t >> 2, s0 = t & 3;
    const int r1 = r0 + 64;
    const int loA  = r0 * 32 + ((s0 ^ ((r0 >> 1) & 3)) << 3);
    const int loB0 = loA;
    const int loB1 = r1 * 32 + ((s0 ^ ((r1 >> 1) & 3)) << 3);

    const bf16* Ap  = A + (size_t)(brow0 + r0) * lda + s0 * 8;
    const bf16* Bp0 = B + (size_t)(c0 + r0) * K + s0 * 8;
    const bf16* Bp1 = B + (size_t)(c0 + r1) * K + s0 * 8;

    f32x4 acc[2][4];
#pragma unroll
    for (int m = 0; m < 2; ++m)
#pragma unroll
        for (int n = 0; n < 4; ++n) {
            f32x4 z = {0.f, 0.f, 0.f, 0.f};
            acc[m][n] = z;
        }

    const int nk = K >> 5;
    uint4 pa  = *(const uint4*)(Ap);
    uint4 pb0 = *(const uint4*)(Bp0);
    uint4 pb1 = *(const uint4*)(Bp1);

    const int kg = lane >> 4;
    const int lr = lane & 15;

    for (int ks = 0; ks < nk; ++ks) {
        uint4 ca = pa, cb0 = pb0, cb1 = pb1;
        if (ks + 1 < nk) {
            const int kk = (ks + 1) << 5;
            pa  = *(const uint4*)(Ap + kk);
            pb0 = *(const uint4*)(Bp0 + kk);
            pb1 = *(const uint4*)(Bp1 + kk);
        }
        __syncthreads();
        *(uint4*)&Abuf[loA]  = ca;
        *(uint4*)&Bbuf[loB0] = cb0;
        *(uint4*)&Bbuf[loB1] = cb1;
        __syncthreads();

        bf16x8 af[2], bfr[4];
#pragma unroll
        for (int m = 0; m < 2; ++m) {
            const int row = wr * 32 + m * 16 + lr;
            af[m] = *(bf16x8*)&Abuf[row * 32 + ((kg ^ ((row >> 1) & 3)) << 3)];
        }
#pragma unroll
        for (int n = 0; n < 4; ++n) {
            const int col = wc * 64 + n * 16 + lr;
            bfr[n] = *(bf16x8*)&Bbuf[col * 32 + ((kg ^ ((col >> 1) & 3)) << 3)];
        }
#pragma unroll
        for (int m = 0; m < 2; ++m)
#pragma unroll
            for (int n = 0; n < 4; ++n)
                acc[m][n] = __builtin_amdgcn_mfma_f32_16x16x32_bf16(af[m], bfr[n], acc[m][n], 0, 0, 0);
    }

#pragma unroll
    for (int m = 0; m < 2; ++m) {
#pragma unroll
        for (int n = 0; n < 4; ++n) {
#pragma unroll
            for (int r = 0; r < 4; ++r) {
                const int row = brow0 + wr * 32 + m * 16 + kg * 4 + r;
                const int col = c0 + wc * 64 + n * 16 + lr;
                const float mv = maskf[row * U6 + u];
                const size_t go = ((size_t)(b0 + row) * U6 + u) * 512 + col;
                out_hs[go] = (mv != 0.f)
                    ? acc[m][n][r] + (float)h16[(size_t)row * 3072 + u * 512 + col]
                    : hs_in[go];
            }
        }
    }
}

// ---------------------------------------------------------------------------
// tiny attention over bf16 qkv: qkv[bl][u*2304 + (q:128|k:128|v:2048)],
// per-batch row stride 13824. ctx written in bf16.
// ---------------------------------------------------------------------------
__global__ __launch_bounds__(256) void attn_kernel(
    const bf16* __restrict__ qkv, bf16* __restrict__ ctx)
{
    const int bl = blockIdx.x, hh = blockIdx.y, t = threadIdx.x;
    __shared__ float qs[6][32], ks[6][32], att[6][8];
    if (t < 192) {
        int u = t >> 5, d = t & 31;
        const size_t rowb = (size_t)bl * 13824 + (size_t)u * 2304;
        qs[u][d] = (float)qkv[rowb + hh * 32 + d];
        ks[u][d] = (float)qkv[rowb + 128 + hh * 32 + d];
    }
    __syncthreads();
    if (t < 36) {
        int u = t / 6, n = t - (t / 6) * 6;
        float a = 0.f;
        for (int d = 0; d < 32; ++d) a += qs[u][d] * ks[n][d];
        att[u][n] = a * 0.17677669529663687f;
    }
    __syncthreads();
    if (t < 6) {
        float mx = att[t][0];
        for (int n = 1; n < 6; ++n) mx = fmaxf(mx, att[t][n]);
        float e[6], s = 0.f;
        for (int n = 0; n < 6; ++n) { e[n] = expf(att[t][n] - mx); s += e[n]; }
        for (int n = 0; n < 6; ++n) att[t][n] = e[n] / s;
    }
    __syncthreads();
    for (int e0 = t; e0 < 512; e0 += 256) {
        float vv[6];
#pragma unroll
        for (int n = 0; n < 6; ++n)
            vv[n] = (float)qkv[(size_t)bl * 13824 + (size_t)n * 2304 + 256 + hh * 512 + e0];
#pragma unroll
        for (int u = 0; u < 6; ++u) {
            float a = 0.f;
#pragma unroll
            for (int n = 0; n < 6; ++n) a += att[u][n] * vv[n];
            ctx[((size_t)bl * U6 + u) * 2048 + hh * 512 + e0] = (bf16)a;
        }
    }
}

// ---------------------------------------------------------------------------
extern "C" void kernel_launch(void* const* d_in, const int* in_sizes, int n_in,
                              void* d_out, int out_size, void* d_ws, size_t ws_size,
                              hipStream_t stream)
{
    const float* x     = (const float*)d_in[0];
    const float* hs    = (const float*)d_in[1];
    const float* cs    = (const float*)d_in[2];
    const float* Wk    = (const float*)d_in[3];
    const float* bk    = (const float*)d_in[4];
    const float* Wv    = (const float*)d_in[5];
    const float* bv    = (const float*)d_in[6];
    const float* Wq_in = (const float*)d_in[7];
    const float* Wq_c  = (const float*)d_in[8];
    const float* Wk_c  = (const float*)d_in[9];
    const float* Wv_c  = (const float*)d_in[10];
    const float* Wo_c  = (const float*)d_in[11];
    const float* W_ih  = (const float*)d_in[12];
    const float* W_hh  = (const float*)d_in[13];
    const float* b_ih  = (const float*)d_in[14];
    const float* b_hh  = (const float*)d_in[15];

    float* out_hs = (float*)d_out;
    float* out_cs = out_hs + (size_t)BFULL * U6 * 512;

    // ---- workspace: fixed (full-batch) part ----
    size_t off = 0;
    auto alloc = [&](size_t bytes) {
        void* p = (char*)d_ws + off;
        off = (off + bytes + 255) & ~255UL;
        return p;
    };
    bf16*  Wg    = (bf16*)alloc(6UL * 2048 * 928 * 2);
    bf16*  Wqkv  = (bf16*)alloc(6UL * 2304 * 512 * 2);
    bf16*  WoT   = (bf16*)alloc(6UL * 512 * 2048 * 2);
    bf16*  WvT   = (bf16*)alloc(512UL * 512 * 2);
    bf16*  x16   = (bf16*)alloc((size_t)BFULL * 512 * 2);
    bf16*  A_g   = (bf16*)alloc((size_t)BFULL * U6 * 928 * 2);
    float* Wk_p  = (float*)alloc(512UL * 64 * 4);
    float* Wq_p  = (float*)alloc(6UL * 512 * 64 * 4);
    float* coef  = (float*)alloc((size_t)BFULL * U6 * 4);
    float* maskf = (float*)alloc((size_t)BFULL * U6 * 4);
    const size_t fixedB = off;

    // ---- chunked part: qkv16 (27648 B/row) + ctx16 (24576 B/row); h16 ----
    const size_t perRow = 52224 + 6144;
    int NC = 1;
    while (NC < 16 && fixedB + (size_t)(BFULL / NC) * perRow + 4096 > ws_size) NC *= 2;
    const int Bc = BFULL / NC;

    char*  R1    = (char*)alloc((size_t)Bc * 52224);
    bf16*  h16   = (bf16*)alloc((size_t)Bc * 6144);

    bf16*  qkv16 = (bf16*)R1;
    bf16*  ctx16 = (bf16*)(R1 + (size_t)Bc * 27648);

    // ---- once per call: weight builds + front-end (full batch) ----
    {
        size_t n = 6UL * 2048 * 928;
        build_wg<<<(int)((n + 255) / 256), 256, 0, stream>>>(W_ih, W_hh, b_ih, b_hh, Wg);
    }
    transpose_cvt<<<dim3(4, 16, U6), 256, 0, stream>>>(Wq_c, Wqkv, 512, 128, 128, 0,
                                                       512L * 128, 2304L * 512);
    transpose_cvt<<<dim3(4, 16, U6), 256, 0, stream>>>(Wk_c, Wqkv, 512, 128, 128, 128,
                                                       512L * 128, 2304L * 512);
    transpose_cvt<<<dim3(64, 16, U6), 256, 0, stream>>>(Wv_c, Wqkv, 512, 2048, 2048, 256,
                                                        512L * 2048, 2304L * 512);
    transpose_cvt<<<dim3(16, 64, U6), 256, 0, stream>>>(Wo_c, WoT, 2048, 512, 512, 0,
                                                        2048L * 512, 512L * 2048);
    transpose_cvt<<<dim3(16, 16, 1), 256, 0, stream>>>(Wv, WvT, 512, 400, 400, 0, 0, 0);
    pack_w<<<(7 * 512 * 64 + 255) / 256, 256, 0, stream>>>(Wk, Wq_in, Wk_p, Wq_p);
    cvt16<<<(int)(((size_t)BFULL * 512 + 255) / 256), 256, 0, stream>>>(
        x, x16, (size_t)BFULL * 512);
    score2_kernel<<<BFULL / 4, 384, 0, stream>>>(x, hs, Wk_p, bk, Wq_p, coef, maskf);
    gemm_mfma<2><<<dim3(BFULL / 128, 4, 1), 256, 0, stream>>>(
        x16, 512, 0L, WvT, 0L, nullptr, 0, 0L, 512,
        maskf, bv, coef, (float*)A_g, 0);
    ag_fill<<<(int)(((size_t)BFULL * U6 * 528 + 255) / 256), 256, 0, stream>>>(hs, A_g);

    // ---- chunk loop ----
    for (int c = 0; c < NC; ++c) {
        const int b0 = c * Bc;
        // gates GEMM + fused LSTM (writes h16, cs_out)
        gemm_gates_fused<<<dim3(Bc / 128, 16, U6), 256, 0, stream>>>(
            A_g + (size_t)b0 * 5568, Wg, cs, maskf + (size_t)b0 * U6,
            h16, out_cs, b0);
        // qkv16 = h16 @ Wqkv^T  (M=Bc, N=2304, K=512), bf16 out
        gemm_mfma<3><<<dim3(Bc / 128, 18, U6), 256, 0, stream>>>(
            h16, 3072, 512L, Wqkv, 2304L * 512, (float*)qkv16, 13824, 2304L, 512,
            nullptr, nullptr, nullptr, nullptr, 0);
        attn_kernel<<<dim3(Bc, 4), 256, 0, stream>>>(qkv16, ctx16);
        // hs_out = mask ? ctx @ WoT^T + h16 : hs   (M=Bc, N=512, K=2048)
        gemm_m64_wo<<<dim3(Bc / 64, 4, U6), 256, 0, stream>>>(
            ctx16, 2048, WoT, 512L * 2048, 2048,
            maskf + (size_t)b0 * U6, h16, hs, out_hs, b0);
    }
}